// Round 12
// baseline (245.159 us; speedup 1.0000x reference)
//
#include <hip/hip_runtime.h>
#include <hip/hip_bf16.h>

// CSSM TinyViT block, fused bf16-MFMA implementation for gfx950.
// B=16,H=32,W=32 -> 16384 rows of C=384. T=8, HID=1536.
// Round 12 = round 11 with the pipeline slot-clobber FIXED: consume slot
// k%D first, then refill the freed slot with kb=k+D. W depth 2, P depth 2
// (~105 VGPR, safe under the 128 cliff). Weight stream issues continuously
// (3 loads/iter) instead of 12-load bursts -> better L2 duty cycle.

#define CCH   384          // global row stride (elements)
#define SB    392          // LDS row stride (ushorts): 384 + 8 pad
#define NPIX  16384
#define BMROWS 64
#define NTHR  1024         // 16 waves: 2 pixel-groups x 8 chan-slots
#define LNEPS 1e-6f
#define HBUF  (BMROWS * SB)   // 25088 ushorts = 49KB per buffer

typedef __attribute__((ext_vector_type(8))) short bf8_t;   // 8 x bf16
typedef __attribute__((ext_vector_type(4))) float f4_t;    // 4 x f32
typedef __attribute__((ext_vector_type(8))) unsigned short us8_t;

// workspace offsets (ushort units). Each 16x16x32 W-tile = 512 bf16 = 1KB.
// K-MAJOR tile order: tile = kb * (N/16) + n16   (kb = K/32 block)
#define OFF_WU 0u
#define OFF_WG 147456u      // 288 tiles * 512
#define OFF_A  294912u
#define OFF_W1 442368u      // 384x1536 -> 1152 tiles
#define OFF_W2 1032192u     // 1536x384 -> 1152 tiles

__device__ __forceinline__ unsigned short f2bf(float f) {
  return __builtin_bit_cast(unsigned short, __float2bfloat16(f));  // HW RNE cvt
}
__device__ __forceinline__ unsigned pack2(float lo, float hi) {
  return (unsigned)f2bf(lo) | ((unsigned)f2bf(hi) << 16);
}
__device__ __forceinline__ float ulo(unsigned u) {
  union { unsigned x; float f; } v; v.x = u << 16; return v.f;
}
__device__ __forceinline__ float uhi(unsigned u) {
  union { unsigned x; float f; } v; v.x = u & 0xffff0000u; return v.f;
}
// sigmoid(z) = 1/(1+2^(-z*log2e))
__device__ __forceinline__ float fsigmoid(float z) {
  return __builtin_amdgcn_rcpf(1.f + exp2f(z * -1.44269504088896f));
}

// Pack all five f32 weights into bf16 fragment order, k-major tiles:
// P[off + tile*512 + lane*8 + j] = W[kb*32 + (lane>>4)*8 + j][n16*16 + (lane&15)]
// Used as the MFMA A-operand: A[row=n][k] = W[k][n] (i.e. W^T).
__global__ void pack_all(const float* __restrict__ Wu, const float* __restrict__ Wg,
                         const float* __restrict__ A,  const float* __restrict__ W1,
                         const float* __restrict__ W2, unsigned short* __restrict__ P) {
  const int gid = blockIdx.x * blockDim.x + threadIdx.x;
  const int l = gid & 63;
  int tile = gid >> 6;
  const float* W; int N; unsigned off; int t;
  if      (tile <  288) { W = Wu; N = 384;  off = OFF_WU; t = tile;        }
  else if (tile <  576) { W = Wg; N = 384;  off = OFF_WG; t = tile - 288;  }
  else if (tile <  864) { W = A;  N = 384;  off = OFF_A;  t = tile - 576;  }
  else if (tile < 2016) { W = W1; N = 1536; off = OFF_W1; t = tile - 864;  }
  else if (tile < 3168) { W = W2; N = 384;  off = OFF_W2; t = tile - 2016; }
  else return;
  const int ntn = N >> 4;
  const int kb  = t / ntn, n16 = t % ntn;
  const int krow = kb * 32 + ((l >> 4) << 3);
  const int col  = n16 * 16 + (l & 15);
  us8_t pk;
  #pragma unroll
  for (int j = 0; j < 8; ++j) pk[j] = f2bf(W[(size_t)(krow + j) * N + col]);
  *reinterpret_cast<us8_t*>(P + off + ((size_t)t << 9) + (l << 3)) = pk;
}

// acc[2][3] += W^T(3 chan-tiles, packed k-major) * X^T(LDS, 2 pixel-tiles
// at pixel base pb). Software-pipelined, depth 2 for both W and P streams.
// Per iteration: MFMA consumes slot k%2, THEN kb=k+2 is loaded into the
// just-freed slot (k+2)%2 == k%2. All indices compile-time after unroll.
template <int NKB>
__device__ __forceinline__ void gemm_pipe(const unsigned short* sb,
                                          const unsigned short* __restrict__ wt,
                                          int kb0, int ntn, int n16base, int pb,
                                          int lane, f4_t acc[2][3]) {
  const int r    = lane & 15;
  const int koff = (lane >> 4) << 3;
  const unsigned short* bt0 =
      wt + (((size_t)(kb0 * ntn + n16base)) << 9) + (lane << 3);
  const size_t bstr = (size_t)ntn << 9;
  bf8_t W[2][3], P[2][2];
#define LDW_(s, kb) { const unsigned short* bt = bt0 + (size_t)(kb) * bstr;      \
    W[s][0] = *reinterpret_cast<const bf8_t*>(bt);                               \
    W[s][1] = *reinterpret_cast<const bf8_t*>(bt + 512);                         \
    W[s][2] = *reinterpret_cast<const bf8_t*>(bt + 1024); }
#define LDP_(s, kb) { const int ac = (kb) * 32 + koff;                           \
    P[s][0] = *reinterpret_cast<const bf8_t*>(&sb[(pb + r) * SB + ac]);          \
    P[s][1] = *reinterpret_cast<const bf8_t*>(&sb[(pb + 16 + r) * SB + ac]); }
#define MFM_(s, q) { _Pragma("unroll") for (int ct = 0; ct < 3; ++ct) {          \
    acc[0][ct] = __builtin_amdgcn_mfma_f32_16x16x32_bf16(W[s][ct], P[q][0],      \
                                                         acc[0][ct], 0, 0, 0);  \
    acc[1][ct] = __builtin_amdgcn_mfma_f32_16x16x32_bf16(W[s][ct], P[q][1],      \
                                                         acc[1][ct], 0, 0, 0); } }
  LDW_(0, 0) LDW_(1, 1)
  LDP_(0, 0) LDP_(1, 1)
  #pragma unroll
  for (int k = 0; k < NKB; ++k) {
    MFM_(k % 2, k % 2)                      // consume slot k%2 (kb = k)
    if (k + 2 < NKB) {                      // refill freed slot with kb = k+2
      LDW_((k + 2) % 2, k + 2)
      LDP_((k + 2) % 2, k + 2)
    }
  }
#undef LDW_
#undef LDP_
#undef MFM_
}

// write transposed C/D tile into padded bf16 LDS [pix][chan] buffer:
// each (pt,ct) quad = 4 consecutive chans of one pixel -> one ds_write_b64.
__device__ __forceinline__ void write_tile(unsigned short* sb, const f4_t t[2][3],
                                           int pb, int ch0, int lane) {
  const int pixb = lane & 15;
  #pragma unroll
  for (int pt = 0; pt < 2; ++pt) {
    const int pix = pb + pt * 16 + pixb;
    #pragma unroll
    for (int ct = 0; ct < 3; ++ct) {
      uint2 v;
      v.x = pack2(t[pt][ct][0], t[pt][ct][1]);
      v.y = pack2(t[pt][ct][2], t[pt][ct][3]);
      *reinterpret_cast<uint2*>(&sb[pix * SB + ch0 + ct * 16]) = v;
    }
  }
}

__device__ __forceinline__ void zero_acc(f4_t a[2][3]) {
  #pragma unroll
  for (int pt = 0; pt < 2; ++pt)
    #pragma unroll
    for (int ct = 0; ct < 3; ++ct) a[pt][ct] = (f4_t){0.f, 0.f, 0.f, 0.f};
}

__global__ __launch_bounds__(NTHR, 1) void cssm_main(
    const float* __restrict__ x,
    const float* __restrict__ n1s, const float* __restrict__ n1b,
    const float* __restrict__ bu, const float* __restrict__ bg,
    const float* __restrict__ n2s, const float* __restrict__ n2b,
    const float* __restrict__ b1, const float* __restrict__ b2,
    const unsigned short* __restrict__ wp,
    float* __restrict__ out) {
  __shared__ unsigned short sm[3 * HBUF];   // bA | bB | bC
  __shared__ float part[64][8][2];          // per-(pixel,chan-slot) LN2 partials
  __shared__ float srow[64][2];             // LN2 mu, rs per pixel
  unsigned short* bA = sm;                  // xn -> h ping -> xn2
  unsigned short* bB = sm + HBUF;           // h pong -> m even chunks
  unsigned short* bC = sm + 2 * HBUF;       // m odd chunks

  const int tid = threadIdx.x;
  const int lane = tid & 63;
  const int wv = tid >> 6;                  // 0..15
  const int nw = wv & 7;                    // chan-slot: chans nw*48..+47
  const int pb = (wv >> 3) << 5;            // pixel base: 0 or 32
  const int r0 = blockIdx.x * BMROWS;
  const int pixb = lane & 15;
  const int ch0  = nw * 48 + ((lane >> 4) << 2);

  // ---------------- Phase A: LN1(x) -> bA (bf16 [pix][chan], padded) -------
  {
    const int row = tid >> 4, seg = tid & 15;    // 16 thr/row, 24 elems each
    const float* xr = x + (size_t)(r0 + row) * CCH + seg * 24;
    float v[24];
    float s = 0.f, s2 = 0.f;
    #pragma unroll
    for (int i = 0; i < 6; ++i) {
      const f4_t t = reinterpret_cast<const f4_t*>(xr)[i];
      #pragma unroll
      for (int j = 0; j < 4; ++j) { const float f = t[j]; v[i * 4 + j] = f; s += f; s2 += f * f; }
    }
    #pragma unroll
    for (int o = 1; o < 16; o <<= 1) { s += __shfl_xor(s, o, 64); s2 += __shfl_xor(s2, o, 64); }
    const float mu = s * (1.f / CCH);
    const float rs = rsqrtf(fmaxf(s2 * (1.f / CCH) - mu * mu, 0.f) + LNEPS);
    #pragma unroll
    for (int g8 = 0; g8 < 3; ++g8) {
      us8_t pk;
      #pragma unroll
      for (int j = 0; j < 8; ++j) {
        const int colc = seg * 24 + g8 * 8 + j;
        pk[j] = f2bf((v[g8 * 8 + j] - mu) * rs * n1s[colc] + n1b[colc]);
      }
      *reinterpret_cast<us8_t*>(&bA[row * SB + seg * 24 + g8 * 8]) = pk;
    }
  }
  __syncthreads();

  // ---------------- Phase A2: g, c -> packed regs; h1 -> bB ----------------
  f4_t acc[2][3];
  unsigned gp[2][3][2], cp[2][3][2];
  zero_acc(acc);
  gemm_pipe<12>(bA, wp + OFF_WG, 0, 24, nw * 3, pb, lane, acc);
  #pragma unroll
  for (int ct = 0; ct < 3; ++ct) {
    const f4_t bgq = *reinterpret_cast<const f4_t*>(&bg[ch0 + ct * 16]);
    #pragma unroll
    for (int pt = 0; pt < 2; ++pt) {
      gp[pt][ct][0] = pack2(fsigmoid(acc[pt][ct][0] + bgq[0]),
                            fsigmoid(acc[pt][ct][1] + bgq[1]));
      gp[pt][ct][1] = pack2(fsigmoid(acc[pt][ct][2] + bgq[2]),
                            fsigmoid(acc[pt][ct][3] + bgq[3]));
    }
  }
  zero_acc(acc);
  gemm_pipe<12>(bA, wp + OFF_WU, 0, 24, nw * 3, pb, lane, acc);
  #pragma unroll
  for (int ct = 0; ct < 3; ++ct) {
    const f4_t buq = *reinterpret_cast<const f4_t*>(&bu[ch0 + ct * 16]);
    #pragma unroll
    for (int pt = 0; pt < 2; ++pt) {
      #pragma unroll
      for (int p = 0; p < 2; ++p) {
        const unsigned g = gp[pt][ct][p];
        const float c0 = (1.f - ulo(g)) * (acc[pt][ct][2 * p]     + buq[2 * p]);
        const float c1 = (1.f - uhi(g)) * (acc[pt][ct][2 * p + 1] + buq[2 * p + 1]);
        acc[pt][ct][2 * p] = c0; acc[pt][ct][2 * p + 1] = c1;
        cp[pt][ct][p] = pack2(c0, c1);
      }
    }
  }
  write_tile(bB, acc, pb, ch0, lane);       // h1 = c (bA reads done above)
  __syncthreads();

  // ---------------- Phase B: h' = g*(h@A) + c, ping-pong bB/bA -------------
  {
    unsigned short* cur = bB;
    unsigned short* alt = bA;
    #pragma unroll 1
    for (int stp = 0; stp < 7; ++stp) {     // h2..h8
      zero_acc(acc);
      gemm_pipe<12>(cur, wp + OFF_A, 0, 24, nw * 3, pb, lane, acc);
      #pragma unroll
      for (int pt = 0; pt < 2; ++pt)
        #pragma unroll
        for (int ct = 0; ct < 3; ++ct)
          #pragma unroll
          for (int p = 0; p < 2; ++p) {
            const unsigned g = gp[pt][ct][p], c = cp[pt][ct][p];
            acc[pt][ct][2 * p]     = ulo(g) * acc[pt][ct][2 * p]     + ulo(c);
            acc[pt][ct][2 * p + 1] = uhi(g) * acc[pt][ct][2 * p + 1] + uhi(c);
          }
      if (stp < 6) {
        write_tile(alt, acc, pb, ch0, lane);  // write buffer nobody is reading
        unsigned short* t = cur; cur = alt; alt = t;
        __syncthreads();
      }
    }
  }
  // last recurrence reads hit bB (fenced later); bA reads fenced at stp5.

  // ------- Phase C: y = x + h8 -> out (f32 scratch); LN2 -> xn2 in bA ------
  #pragma unroll
  for (int pt = 0; pt < 2; ++pt) {
    const int pix = pb + pt * 16 + pixb;
    float s = 0.f, s2 = 0.f;
    #pragma unroll
    for (int ct = 0; ct < 3; ++ct) {
      const size_t pos = (size_t)(r0 + pix) * CCH + ch0 + ct * 16;
      const f4_t xq = *reinterpret_cast<const f4_t*>(&x[pos]);
      f4_t yq;
      #pragma unroll
      for (int j = 0; j < 4; ++j) {
        const float y = xq[j] + acc[pt][ct][j];
        yq[j] = y; acc[pt][ct][j] = y;
        s += y; s2 += y * y;
      }
      *reinterpret_cast<f4_t*>(&out[pos]) = yq;   // same-thread reread in E
    }
    s += __shfl_xor(s, 16, 64); s2 += __shfl_xor(s2, 16, 64);
    s += __shfl_xor(s, 32, 64); s2 += __shfl_xor(s2, 32, 64);
    if (lane < 16) { part[pix][nw][0] = s; part[pix][nw][1] = s2; }
  }
  __syncthreads();
  if (tid < 64) {
    float s = 0.f, s2 = 0.f;
    #pragma unroll
    for (int w = 0; w < 8; ++w) { s += part[tid][w][0]; s2 += part[tid][w][1]; }
    const float mu = s * (1.f / CCH);
    srow[tid][0] = mu;
    srow[tid][1] = rsqrtf(fmaxf(s2 * (1.f / CCH) - mu * mu, 0.f) + LNEPS);
  }
  __syncthreads();
  {
    f4_t scq[3], bsq[3];
    #pragma unroll
    for (int ct = 0; ct < 3; ++ct) {
      scq[ct] = *reinterpret_cast<const f4_t*>(&n2s[ch0 + ct * 16]);
      bsq[ct] = *reinterpret_cast<const f4_t*>(&n2b[ch0 + ct * 16]);
    }
    #pragma unroll
    for (int pt = 0; pt < 2; ++pt) {
      const int pix = pb + pt * 16 + pixb;
      const float mu = srow[pix][0], rs = srow[pix][1];
      #pragma unroll
      for (int ct = 0; ct < 3; ++ct)
        #pragma unroll
        for (int j = 0; j < 4; ++j)
          acc[pt][ct][j] = (acc[pt][ct][j] - mu) * rs * scq[ct][j] + bsq[ct][j];
    }
    write_tile(bA, acc, pb, ch0, lane);     // xn2 (bA reads fenced at stp5)
  }
  __syncthreads();

  // ------- Phase D: MLP in 4 HID-chunks, m double-buffered bB/bC -----------
  f4_t aco[2][3];
  zero_acc(aco);                            // MFMA-only until E -> AGPR
  #pragma unroll 1
  for (int ch = 0; ch < 4; ++ch) {
    unsigned short* buf = (ch & 1) ? bC : bB;
    zero_acc(acc);
    gemm_pipe<12>(bA, wp + OFF_W1, 0, 96, ch * 24 + nw * 3, pb, lane, acc);
    #pragma unroll
    for (int ct = 0; ct < 3; ++ct) {
      const f4_t b1q = *reinterpret_cast<const f4_t*>(&b1[ch * 384 + ch0 + ct * 16]);
      #pragma unroll
      for (int pt = 0; pt < 2; ++pt)
        #pragma unroll
        for (int j = 0; j < 4; ++j) {
          // gelu(z) = z / (1 + 2^(-2.3021178*(z + 0.044715 z^3)))
          const float z = acc[pt][ct][j] + b1q[j];
          const float m = z * z;
          const float t = z * fmaf(m, 0.044715f, 1.0f);
          const float e = exp2f(t * -2.30211774f);
          acc[pt][ct][j] = z * __builtin_amdgcn_rcpf(1.f + e);
        }
    }
    write_tile(buf, acc, pb, ch0, lane);
    __syncthreads();                        // buf complete; prev buf readers
                                            // passed the previous barrier
    gemm_pipe<12>(buf, wp + OFF_W2, ch * 12, 24, nw * 3, pb, lane, aco);
  }

  // ---------------- Phase E: out = y + mlp + b2 (same-thread reread) -------
  {
    f4_t b2q[3];
    #pragma unroll
    for (int ct = 0; ct < 3; ++ct)
      b2q[ct] = *reinterpret_cast<const f4_t*>(&b2[ch0 + ct * 16]);
    #pragma unroll
    for (int pt = 0; pt < 2; ++pt) {
      const int pix = pb + pt * 16 + pixb;
      #pragma unroll
      for (int ct = 0; ct < 3; ++ct) {
        const size_t pos = (size_t)(r0 + pix) * CCH + ch0 + ct * 16;
        const f4_t yq = *reinterpret_cast<const f4_t*>(&out[pos]);
        f4_t o;
        #pragma unroll
        for (int j = 0; j < 4; ++j)
          o[j] = yq[j] + aco[pt][ct][j] + b2q[ct][j];
        *reinterpret_cast<f4_t*>(&out[pos]) = o;
      }
    }
  }
}

extern "C" void kernel_launch(void* const* d_in, const int* in_sizes, int n_in,
                              void* d_out, int out_size, void* d_ws, size_t ws_size,
                              hipStream_t stream) {
  const float* x   = (const float*)d_in[0];
  const float* n1s = (const float*)d_in[1];
  const float* n1b = (const float*)d_in[2];
  const float* Wu  = (const float*)d_in[3];
  const float* bu  = (const float*)d_in[4];
  const float* Wg  = (const float*)d_in[5];
  const float* bg  = (const float*)d_in[6];
  const float* A   = (const float*)d_in[7];
  const float* n2s = (const float*)d_in[8];
  const float* n2b = (const float*)d_in[9];
  const float* W1  = (const float*)d_in[10];
  const float* b1  = (const float*)d_in[11];
  const float* W2  = (const float*)d_in[12];
  const float* b2  = (const float*)d_in[13];
  unsigned short* wp = (unsigned short*)d_ws;
  float* out = (float*)d_out;

  // pack all weights to bf16 fragment order (one launch; 3168 tiles * 64 lanes)
  pack_all<<<(3168 * 64) / 256, 256, 0, stream>>>(Wu, Wg, A, W1, W2, wp);

  cssm_main<<<NPIX / BMROWS, NTHR, 0, stream>>>(
      x, n1s, n1b, bu, bg, n2s, n2b, b1, b2, wp, out);
}

// Round 13
// 129.234 us; speedup vs baseline: 1.8970x; 1.8970x over previous
//
#include <hip/hip_runtime.h>
#include <hip/hip_bf16.h>

// CSSM TinyViT block, fused bf16-MFMA implementation for gfx950.
// B=16,H=32,W=32 -> 16384 rows of C=384. T=8, HID=1536.
// Round 13 = round 10 with the 1024-thr block split into TWO independent
// 512-thr blocks (32 pixels each), 2 blocks/CU: same wave count and weight
// traffic, but decoupled barrier domains -> one block's waves fill the
// MFMA/VALU pipes while the other drains at __syncthreads. Inner gemm is
// the compiler-scheduled #pragma unroll 4 form (r6/r11/r12 hand pipelines
// all spilled; this is the proven local optimum).

#define CCH   384          // global row stride (elements)
#define SB    392          // LDS row stride (ushorts): 384 + 8 pad
#define NPIX  16384
#define BMROWS 32          // pixels per block
#define NTHR  512          // 8 waves; wave owns 48 chans x 32 pixels
#define LNEPS 1e-6f
#define HBUF  (BMROWS * SB)   // 12544 ushorts = 24.5KB per buffer

typedef __attribute__((ext_vector_type(8))) short bf8_t;   // 8 x bf16
typedef __attribute__((ext_vector_type(4))) float f4_t;    // 4 x f32
typedef __attribute__((ext_vector_type(8))) unsigned short us8_t;

// workspace offsets (ushort units). Each 16x16x32 W-tile = 512 bf16 = 1KB.
// K-MAJOR tile order: tile = kb * (N/16) + n16   (kb = K/32 block)
#define OFF_WU 0u
#define OFF_WG 147456u      // 288 tiles * 512
#define OFF_A  294912u
#define OFF_W1 442368u      // 384x1536 -> 1152 tiles
#define OFF_W2 1032192u     // 1536x384 -> 1152 tiles

__device__ __forceinline__ unsigned short f2bf(float f) {
  return __builtin_bit_cast(unsigned short, __float2bfloat16(f));  // HW RNE cvt
}
__device__ __forceinline__ unsigned pack2(float lo, float hi) {
  return (unsigned)f2bf(lo) | ((unsigned)f2bf(hi) << 16);
}
__device__ __forceinline__ float ulo(unsigned u) {
  union { unsigned x; float f; } v; v.x = u << 16; return v.f;
}
__device__ __forceinline__ float uhi(unsigned u) {
  union { unsigned x; float f; } v; v.x = u & 0xffff0000u; return v.f;
}
// sigmoid(z) = 1/(1+2^(-z*log2e))
__device__ __forceinline__ float fsigmoid(float z) {
  return __builtin_amdgcn_rcpf(1.f + exp2f(z * -1.44269504088896f));
}

// Pack all five f32 weights into bf16 fragment order, k-major tiles:
// P[off + tile*512 + lane*8 + j] = W[kb*32 + (lane>>4)*8 + j][n16*16 + (lane&15)]
// Used as the MFMA A-operand: A[row=n][k] = W[k][n] (i.e. W^T).
__global__ void pack_all(const float* __restrict__ Wu, const float* __restrict__ Wg,
                         const float* __restrict__ A,  const float* __restrict__ W1,
                         const float* __restrict__ W2, unsigned short* __restrict__ P) {
  const int gid = blockIdx.x * blockDim.x + threadIdx.x;
  const int l = gid & 63;
  int tile = gid >> 6;
  const float* W; int N; unsigned off; int t;
  if      (tile <  288) { W = Wu; N = 384;  off = OFF_WU; t = tile;        }
  else if (tile <  576) { W = Wg; N = 384;  off = OFF_WG; t = tile - 288;  }
  else if (tile <  864) { W = A;  N = 384;  off = OFF_A;  t = tile - 576;  }
  else if (tile < 2016) { W = W1; N = 1536; off = OFF_W1; t = tile - 864;  }
  else if (tile < 3168) { W = W2; N = 384;  off = OFF_W2; t = tile - 2016; }
  else return;
  const int ntn = N >> 4;
  const int kb  = t / ntn, n16 = t % ntn;
  const int krow = kb * 32 + ((l >> 4) << 3);
  const int col  = n16 * 16 + (l & 15);
  us8_t pk;
  #pragma unroll
  for (int j = 0; j < 8; ++j) pk[j] = f2bf(W[(size_t)(krow + j) * N + col]);
  *reinterpret_cast<us8_t*>(P + off + ((size_t)t << 9) + (l << 3)) = pk;
}

// acc[2][3] += W^T(3 chan-tiles, packed k-major) * X^T(LDS, 2 pixel-tiles).
// acc[pt][ct]: D[chan][pix] 16x16 tiles; lane holds 4 consecutive chans of
// pixel pt*16 + (lane&15). Compiler-scheduled (#pragma unroll 4).
template <int NKB>
__device__ __forceinline__ void gemm_acc(const unsigned short* sb,
                                         const unsigned short* __restrict__ wt,
                                         int kb0, int ntn, int n16base,
                                         int lane, f4_t acc[2][3]) {
  const int r    = lane & 15;
  const int koff = (lane >> 4) << 3;
  #pragma unroll 4
  for (int kb = 0; kb < NKB; ++kb) {
    const int ac = kb * 32 + koff;
    bf8_t p[2];                       // B-operand: pixel tiles from LDS
    p[0] = *reinterpret_cast<const bf8_t*>(&sb[r * SB + ac]);
    p[1] = *reinterpret_cast<const bf8_t*>(&sb[(16 + r) * SB + ac]);
    const unsigned short* bt =
        wt + (((size_t)((kb0 + kb) * ntn + n16base) << 9) + (lane << 3));
    #pragma unroll
    for (int ct = 0; ct < 3; ++ct) {
      const bf8_t w = *reinterpret_cast<const bf8_t*>(bt + (ct << 9));
      acc[0][ct] = __builtin_amdgcn_mfma_f32_16x16x32_bf16(w, p[0], acc[0][ct], 0, 0, 0);
      acc[1][ct] = __builtin_amdgcn_mfma_f32_16x16x32_bf16(w, p[1], acc[1][ct], 0, 0, 0);
    }
  }
}

// write transposed C/D tile into padded bf16 LDS [pix][chan] buffer:
// each (pt,ct) quad = 4 consecutive chans of one pixel -> one ds_write_b64.
__device__ __forceinline__ void write_tile(unsigned short* sb, const f4_t t[2][3],
                                           int ch0, int lane) {
  const int pixb = lane & 15;
  #pragma unroll
  for (int pt = 0; pt < 2; ++pt) {
    const int pix = pt * 16 + pixb;
    #pragma unroll
    for (int ct = 0; ct < 3; ++ct) {
      uint2 v;
      v.x = pack2(t[pt][ct][0], t[pt][ct][1]);
      v.y = pack2(t[pt][ct][2], t[pt][ct][3]);
      *reinterpret_cast<uint2*>(&sb[pix * SB + ch0 + ct * 16]) = v;
    }
  }
}

__device__ __forceinline__ void zero_acc(f4_t a[2][3]) {
  #pragma unroll
  for (int pt = 0; pt < 2; ++pt)
    #pragma unroll
    for (int ct = 0; ct < 3; ++ct) a[pt][ct] = (f4_t){0.f, 0.f, 0.f, 0.f};
}

__global__ __launch_bounds__(NTHR, 4) void cssm_main(
    const float* __restrict__ x,
    const float* __restrict__ n1s, const float* __restrict__ n1b,
    const float* __restrict__ bu, const float* __restrict__ bg,
    const float* __restrict__ n2s, const float* __restrict__ n2b,
    const float* __restrict__ b1, const float* __restrict__ b2,
    const unsigned short* __restrict__ wp,
    float* __restrict__ out) {
  __shared__ unsigned short sm[3 * HBUF];   // bA | bB | bC (24.5KB each)
  __shared__ float part[BMROWS][8][2];      // per-(pixel,chan-slot) LN2 partials
  __shared__ float srow[BMROWS][2];         // LN2 mu, rs per pixel
  unsigned short* bA = sm;                  // xn -> h ping -> xn2
  unsigned short* bB = sm + HBUF;           // h pong -> m even chunks
  unsigned short* bC = sm + 2 * HBUF;       // m odd chunks

  const int tid = threadIdx.x;
  const int lane = tid & 63;
  const int nw = tid >> 6;                  // chan-slot: chans nw*48..+47
  const int r0 = blockIdx.x * BMROWS;
  const int pixb = lane & 15;
  const int ch0  = nw * 48 + ((lane >> 4) << 2);

  // ---------------- Phase A: LN1(x) -> bA (bf16 [pix][chan], padded) -------
  {
    const int row = tid >> 4, seg = tid & 15;    // 16 thr/row, 24 elems each
    const float* xr = x + (size_t)(r0 + row) * CCH + seg * 24;
    float v[24];
    float s = 0.f, s2 = 0.f;
    #pragma unroll
    for (int i = 0; i < 6; ++i) {
      const f4_t t = reinterpret_cast<const f4_t*>(xr)[i];
      #pragma unroll
      for (int j = 0; j < 4; ++j) { const float f = t[j]; v[i * 4 + j] = f; s += f; s2 += f * f; }
    }
    #pragma unroll
    for (int o = 1; o < 16; o <<= 1) { s += __shfl_xor(s, o, 64); s2 += __shfl_xor(s2, o, 64); }
    const float mu = s * (1.f / CCH);
    const float rs = rsqrtf(fmaxf(s2 * (1.f / CCH) - mu * mu, 0.f) + LNEPS);
    #pragma unroll
    for (int g8 = 0; g8 < 3; ++g8) {
      us8_t pk;
      #pragma unroll
      for (int j = 0; j < 8; ++j) {
        const int colc = seg * 24 + g8 * 8 + j;
        pk[j] = f2bf((v[g8 * 8 + j] - mu) * rs * n1s[colc] + n1b[colc]);
      }
      *reinterpret_cast<us8_t*>(&bA[row * SB + seg * 24 + g8 * 8]) = pk;
    }
  }
  __syncthreads();

  // ---------------- Phase A2: g, c -> packed regs; h1 -> bB ----------------
  f4_t acc[2][3];
  unsigned gp[2][3][2], cp[2][3][2];
  zero_acc(acc);
  gemm_acc<12>(bA, wp + OFF_WG, 0, 24, nw * 3, lane, acc);
  #pragma unroll
  for (int ct = 0; ct < 3; ++ct) {
    const f4_t bgq = *reinterpret_cast<const f4_t*>(&bg[ch0 + ct * 16]);
    #pragma unroll
    for (int pt = 0; pt < 2; ++pt) {
      gp[pt][ct][0] = pack2(fsigmoid(acc[pt][ct][0] + bgq[0]),
                            fsigmoid(acc[pt][ct][1] + bgq[1]));
      gp[pt][ct][1] = pack2(fsigmoid(acc[pt][ct][2] + bgq[2]),
                            fsigmoid(acc[pt][ct][3] + bgq[3]));
    }
  }
  zero_acc(acc);
  gemm_acc<12>(bA, wp + OFF_WU, 0, 24, nw * 3, lane, acc);
  #pragma unroll
  for (int ct = 0; ct < 3; ++ct) {
    const f4_t buq = *reinterpret_cast<const f4_t*>(&bu[ch0 + ct * 16]);
    #pragma unroll
    for (int pt = 0; pt < 2; ++pt) {
      #pragma unroll
      for (int p = 0; p < 2; ++p) {
        const unsigned g = gp[pt][ct][p];
        const float c0 = (1.f - ulo(g)) * (acc[pt][ct][2 * p]     + buq[2 * p]);
        const float c1 = (1.f - uhi(g)) * (acc[pt][ct][2 * p + 1] + buq[2 * p + 1]);
        acc[pt][ct][2 * p] = c0; acc[pt][ct][2 * p + 1] = c1;
        cp[pt][ct][p] = pack2(c0, c1);
      }
    }
  }
  write_tile(bB, acc, ch0, lane);           // h1 = c (bA reads done above)
  __syncthreads();

  // ---------------- Phase B: h' = g*(h@A) + c, ping-pong bB/bA -------------
  {
    unsigned short* cur = bB;
    unsigned short* alt = bA;
    #pragma unroll 1
    for (int stp = 0; stp < 7; ++stp) {     // h2..h8
      zero_acc(acc);
      gemm_acc<12>(cur, wp + OFF_A, 0, 24, nw * 3, lane, acc);
      #pragma unroll
      for (int pt = 0; pt < 2; ++pt)
        #pragma unroll
        for (int ct = 0; ct < 3; ++ct)
          #pragma unroll
          for (int p = 0; p < 2; ++p) {
            const unsigned g = gp[pt][ct][p], c = cp[pt][ct][p];
            acc[pt][ct][2 * p]     = ulo(g) * acc[pt][ct][2 * p]     + ulo(c);
            acc[pt][ct][2 * p + 1] = uhi(g) * acc[pt][ct][2 * p + 1] + uhi(c);
          }
      if (stp < 6) {
        write_tile(alt, acc, ch0, lane);    // write buffer nobody is reading
        unsigned short* t = cur; cur = alt; alt = t;
        __syncthreads();
      }
    }
  }
  // last recurrence reads hit bB (fenced later); bA reads fenced at stp5.

  // ------- Phase C: y = x + h8 -> out (f32 scratch); LN2 -> xn2 in bA ------
  #pragma unroll
  for (int pt = 0; pt < 2; ++pt) {
    const int pix = pt * 16 + pixb;
    float s = 0.f, s2 = 0.f;
    #pragma unroll
    for (int ct = 0; ct < 3; ++ct) {
      const size_t pos = (size_t)(r0 + pix) * CCH + ch0 + ct * 16;
      const f4_t xq = *reinterpret_cast<const f4_t*>(&x[pos]);
      f4_t yq;
      #pragma unroll
      for (int j = 0; j < 4; ++j) {
        const float y = xq[j] + acc[pt][ct][j];
        yq[j] = y; acc[pt][ct][j] = y;
        s += y; s2 += y * y;
      }
      *reinterpret_cast<f4_t*>(&out[pos]) = yq;   // same-thread reread in E
    }
    s += __shfl_xor(s, 16, 64); s2 += __shfl_xor(s2, 16, 64);
    s += __shfl_xor(s, 32, 64); s2 += __shfl_xor(s2, 32, 64);
    if (lane < 16) { part[pix][nw][0] = s; part[pix][nw][1] = s2; }
  }
  __syncthreads();
  if (tid < BMROWS) {
    float s = 0.f, s2 = 0.f;
    #pragma unroll
    for (int w = 0; w < 8; ++w) { s += part[tid][w][0]; s2 += part[tid][w][1]; }
    const float mu = s * (1.f / CCH);
    srow[tid][0] = mu;
    srow[tid][1] = rsqrtf(fmaxf(s2 * (1.f / CCH) - mu * mu, 0.f) + LNEPS);
  }
  __syncthreads();
  {
    f4_t scq[3], bsq[3];
    #pragma unroll
    for (int ct = 0; ct < 3; ++ct) {
      scq[ct] = *reinterpret_cast<const f4_t*>(&n2s[ch0 + ct * 16]);
      bsq[ct] = *reinterpret_cast<const f4_t*>(&n2b[ch0 + ct * 16]);
    }
    #pragma unroll
    for (int pt = 0; pt < 2; ++pt) {
      const int pix = pt * 16 + pixb;
      const float mu = srow[pix][0], rs = srow[pix][1];
      #pragma unroll
      for (int ct = 0; ct < 3; ++ct)
        #pragma unroll
        for (int j = 0; j < 4; ++j)
          acc[pt][ct][j] = (acc[pt][ct][j] - mu) * rs * scq[ct][j] + bsq[ct][j];
    }
    write_tile(bA, acc, ch0, lane);         // xn2 (bA reads fenced at stp5)
  }
  __syncthreads();

  // ------- Phase D: MLP in 4 HID-chunks, m double-buffered bB/bC -----------
  f4_t aco[2][3];
  zero_acc(aco);                            // MFMA-only until E -> AGPR
  #pragma unroll 1
  for (int ch = 0; ch < 4; ++ch) {
    unsigned short* buf = (ch & 1) ? bC : bB;
    zero_acc(acc);
    gemm_acc<12>(bA, wp + OFF_W1, 0, 96, ch * 24 + nw * 3, lane, acc);
    #pragma unroll
    for (int ct = 0; ct < 3; ++ct) {
      const f4_t b1q = *reinterpret_cast<const f4_t*>(&b1[ch * 384 + ch0 + ct * 16]);
      #pragma unroll
      for (int pt = 0; pt < 2; ++pt)
        #pragma unroll
        for (int j = 0; j < 4; ++j) {
          // gelu(z) = z / (1 + 2^(-2.3021178*(z + 0.044715 z^3)))
          const float z = acc[pt][ct][j] + b1q[j];
          const float m = z * z;
          const float t = z * fmaf(m, 0.044715f, 1.0f);
          const float e = exp2f(t * -2.30211774f);
          acc[pt][ct][j] = z * __builtin_amdgcn_rcpf(1.f + e);
        }
    }
    write_tile(buf, acc, ch0, lane);
    __syncthreads();                        // buf complete; prev buf readers
                                            // passed the previous barrier
    gemm_acc<12>(buf, wp + OFF_W2, ch * 12, 24, nw * 3, lane, aco);
  }

  // ---------------- Phase E: out = y + mlp + b2 (same-thread reread) -------
  {
    f4_t b2q[3];
    #pragma unroll
    for (int ct = 0; ct < 3; ++ct)
      b2q[ct] = *reinterpret_cast<const f4_t*>(&b2[ch0 + ct * 16]);
    #pragma unroll
    for (int pt = 0; pt < 2; ++pt) {
      const int pix = pt * 16 + pixb;
      #pragma unroll
      for (int ct = 0; ct < 3; ++ct) {
        const size_t pos = (size_t)(r0 + pix) * CCH + ch0 + ct * 16;
        const f4_t yq = *reinterpret_cast<const f4_t*>(&out[pos]);
        f4_t o;
        #pragma unroll
        for (int j = 0; j < 4; ++j)
          o[j] = yq[j] + aco[pt][ct][j] + b2q[ct][j];
        *reinterpret_cast<f4_t*>(&out[pos]) = o;
      }
    }
  }
}

extern "C" void kernel_launch(void* const* d_in, const int* in_sizes, int n_in,
                              void* d_out, int out_size, void* d_ws, size_t ws_size,
                              hipStream_t stream) {
  const float* x   = (const float*)d_in[0];
  const float* n1s = (const float*)d_in[1];
  const float* n1b = (const float*)d_in[2];
  const float* Wu  = (const float*)d_in[3];
  const float* bu  = (const float*)d_in[4];
  const float* Wg  = (const float*)d_in[5];
  const float* bg  = (const float*)d_in[6];
  const float* A   = (const float*)d_in[7];
  const float* n2s = (const float*)d_in[8];
  const float* n2b = (const float*)d_in[9];
  const float* W1  = (const float*)d_in[10];
  const float* b1  = (const float*)d_in[11];
  const float* W2  = (const float*)d_in[12];
  const float* b2  = (const float*)d_in[13];
  unsigned short* wp = (unsigned short*)d_ws;
  float* out = (float*)d_out;

  // pack all weights to bf16 fragment order (one launch; 3168 tiles * 64 lanes)
  pack_all<<<(3168 * 64) / 256, 256, 0, stream>>>(Wu, Wg, A, W1, W2, wp);

  cssm_main<<<NPIX / BMROWS, NTHR, 0, stream>>>(
      x, n1s, n1b, bu, bg, n2s, n2b, b1, b2, wp, out);
}

// Round 14
// 110.451 us; speedup vs baseline: 2.2196x; 1.1701x over previous
//
#include <hip/hip_runtime.h>
#include <hip/hip_bf16.h>

// CSSM TinyViT block, fused bf16-MFMA implementation for gfx950.
// B=16,H=32,W=32 -> 16384 rows of C=384. T=8, HID=1536.
// Round 14: 12 waves (3/SIMD), ONE 768-thr block of 64 pixels per CU.
// Each wave owns a disjoint 32-chan slice (acc[4][2]) -> zero weight-tile
// duplication (r9's minimal 288KB/CU/phase stream, r13 had 2x) with 1.5x
// r9's latency-hiding waves. + s_setprio(1) around gemm (T5).
// Inner gemm stays the compiler-scheduled #pragma unroll 4 form.

#define CCH   384          // global row stride (elements)
#define SB    392          // LDS row stride (ushorts): 384 + 8 pad
#define NPIX  16384
#define BMROWS 64          // pixels per block
#define NTHR  768          // 12 waves; wave owns 32 chans x 64 pixels
#define LNEPS 1e-6f
#define HBUF  (BMROWS * SB)   // 25088 ushorts = 49KB per buffer

typedef __attribute__((ext_vector_type(8))) short bf8_t;   // 8 x bf16
typedef __attribute__((ext_vector_type(4))) float f4_t;    // 4 x f32
typedef __attribute__((ext_vector_type(8))) unsigned short us8_t;

// workspace offsets (ushort units). Each 16x16x32 W-tile = 512 bf16 = 1KB.
// K-MAJOR tile order: tile = kb * (N/16) + n16   (kb = K/32 block)
#define OFF_WU 0u
#define OFF_WG 147456u      // 288 tiles * 512
#define OFF_A  294912u
#define OFF_W1 442368u      // 384x1536 -> 1152 tiles
#define OFF_W2 1032192u     // 1536x384 -> 1152 tiles

__device__ __forceinline__ unsigned short f2bf(float f) {
  return __builtin_bit_cast(unsigned short, __float2bfloat16(f));  // HW RNE cvt
}
__device__ __forceinline__ unsigned pack2(float lo, float hi) {
  return (unsigned)f2bf(lo) | ((unsigned)f2bf(hi) << 16);
}
__device__ __forceinline__ float ulo(unsigned u) {
  union { unsigned x; float f; } v; v.x = u << 16; return v.f;
}
__device__ __forceinline__ float uhi(unsigned u) {
  union { unsigned x; float f; } v; v.x = u & 0xffff0000u; return v.f;
}
// sigmoid(z) = 1/(1+2^(-z*log2e))
__device__ __forceinline__ float fsigmoid(float z) {
  return __builtin_amdgcn_rcpf(1.f + exp2f(z * -1.44269504088896f));
}

// Pack all five f32 weights into bf16 fragment order, k-major tiles:
// P[off + tile*512 + lane*8 + j] = W[kb*32 + (lane>>4)*8 + j][n16*16 + (lane&15)]
// Used as the MFMA A-operand: A[row=n][k] = W[k][n] (i.e. W^T).
__global__ void pack_all(const float* __restrict__ Wu, const float* __restrict__ Wg,
                         const float* __restrict__ A,  const float* __restrict__ W1,
                         const float* __restrict__ W2, unsigned short* __restrict__ P) {
  const int gid = blockIdx.x * blockDim.x + threadIdx.x;
  const int l = gid & 63;
  int tile = gid >> 6;
  const float* W; int N; unsigned off; int t;
  if      (tile <  288) { W = Wu; N = 384;  off = OFF_WU; t = tile;        }
  else if (tile <  576) { W = Wg; N = 384;  off = OFF_WG; t = tile - 288;  }
  else if (tile <  864) { W = A;  N = 384;  off = OFF_A;  t = tile - 576;  }
  else if (tile < 2016) { W = W1; N = 1536; off = OFF_W1; t = tile - 864;  }
  else if (tile < 3168) { W = W2; N = 384;  off = OFF_W2; t = tile - 2016; }
  else return;
  const int ntn = N >> 4;
  const int kb  = t / ntn, n16 = t % ntn;
  const int krow = kb * 32 + ((l >> 4) << 3);
  const int col  = n16 * 16 + (l & 15);
  us8_t pk;
  #pragma unroll
  for (int j = 0; j < 8; ++j) pk[j] = f2bf(W[(size_t)(krow + j) * N + col]);
  *reinterpret_cast<us8_t*>(P + off + ((size_t)t << 9) + (l << 3)) = pk;
}

// acc[4][2] += W^T(2 chan-tiles, packed k-major) * X^T(LDS, 4 pixel-tiles).
// acc[pt][ct]: D[chan][pix] 16x16 tiles; lane holds 4 consecutive chans of
// pixel pt*16 + (lane&15). Compiler-scheduled (#pragma unroll 4) + setprio.
template <int NKB>
__device__ __forceinline__ void gemm_acc(const unsigned short* sb,
                                         const unsigned short* __restrict__ wt,
                                         int kb0, int ntn, int n16base,
                                         int lane, f4_t acc[4][2]) {
  const int r    = lane & 15;
  const int koff = (lane >> 4) << 3;
  __builtin_amdgcn_s_setprio(1);
  #pragma unroll 4
  for (int kb = 0; kb < NKB; ++kb) {
    const int ac = kb * 32 + koff;
    bf8_t p[4];                       // B-operand: pixel tiles from LDS
    #pragma unroll
    for (int pt = 0; pt < 4; ++pt)
      p[pt] = *reinterpret_cast<const bf8_t*>(&sb[(pt * 16 + r) * SB + ac]);
    const unsigned short* bt =
        wt + (((size_t)((kb0 + kb) * ntn + n16base) << 9) + (lane << 3));
    #pragma unroll
    for (int ct = 0; ct < 2; ++ct) {
      const bf8_t w = *reinterpret_cast<const bf8_t*>(bt + (ct << 9));
      #pragma unroll
      for (int pt = 0; pt < 4; ++pt)
        acc[pt][ct] = __builtin_amdgcn_mfma_f32_16x16x32_bf16(w, p[pt], acc[pt][ct], 0, 0, 0);
    }
  }
  __builtin_amdgcn_s_setprio(0);
}

// write transposed C/D tile into padded bf16 LDS [pix][chan] buffer:
// each (pt,ct) quad = 4 consecutive chans of one pixel -> one ds_write_b64.
__device__ __forceinline__ void write_tile(unsigned short* sb, const f4_t t[4][2],
                                           int ch0, int lane) {
  const int pixb = lane & 15;
  #pragma unroll
  for (int pt = 0; pt < 4; ++pt) {
    const int pix = pt * 16 + pixb;
    #pragma unroll
    for (int ct = 0; ct < 2; ++ct) {
      uint2 v;
      v.x = pack2(t[pt][ct][0], t[pt][ct][1]);
      v.y = pack2(t[pt][ct][2], t[pt][ct][3]);
      *reinterpret_cast<uint2*>(&sb[pix * SB + ch0 + ct * 16]) = v;
    }
  }
}

__device__ __forceinline__ void zero_acc(f4_t a[4][2]) {
  #pragma unroll
  for (int pt = 0; pt < 4; ++pt)
    #pragma unroll
    for (int ct = 0; ct < 2; ++ct) a[pt][ct] = (f4_t){0.f, 0.f, 0.f, 0.f};
}

__global__ __launch_bounds__(NTHR, 1) void cssm_main(
    const float* __restrict__ x,
    const float* __restrict__ n1s, const float* __restrict__ n1b,
    const float* __restrict__ bu, const float* __restrict__ bg,
    const float* __restrict__ n2s, const float* __restrict__ n2b,
    const float* __restrict__ b1, const float* __restrict__ b2,
    const unsigned short* __restrict__ wp,
    float* __restrict__ out) {
  __shared__ unsigned short sm[3 * HBUF];   // bA | bB | bC (49KB each)
  __shared__ float part[BMROWS][12][2];     // per-(pixel,chan-slot) LN2 partials
  __shared__ float srow[BMROWS][2];         // LN2 mu, rs per pixel
  unsigned short* bA = sm;                  // xn -> h ping -> xn2
  unsigned short* bB = sm + HBUF;           // h pong -> m even chunks
  unsigned short* bC = sm + 2 * HBUF;       // m odd chunks

  const int tid = threadIdx.x;
  const int lane = tid & 63;
  const int nw = tid >> 6;                  // chan-slot 0..11: chans nw*32..+31
  const int r0 = blockIdx.x * BMROWS;
  const int pixb = lane & 15;
  const int ch0  = nw * 32 + ((lane >> 4) << 2);

  // ---------------- Phase A: LN1(x) -> bA (first 512 threads) --------------
  if (tid < 512) {
    const int row = tid >> 3, seg = tid & 7;     // 8 thr/row, 48 elems each
    const float* xr = x + (size_t)(r0 + row) * CCH + seg * 48;
    float v[48];
    float s = 0.f, s2 = 0.f;
    #pragma unroll
    for (int i = 0; i < 12; ++i) {
      const f4_t t = reinterpret_cast<const f4_t*>(xr)[i];
      #pragma unroll
      for (int j = 0; j < 4; ++j) { const float f = t[j]; v[i * 4 + j] = f; s += f; s2 += f * f; }
    }
    #pragma unroll
    for (int o = 1; o < 8; o <<= 1) { s += __shfl_xor(s, o, 64); s2 += __shfl_xor(s2, o, 64); }
    const float mu = s * (1.f / CCH);
    const float rs = rsqrtf(fmaxf(s2 * (1.f / CCH) - mu * mu, 0.f) + LNEPS);
    #pragma unroll
    for (int g8 = 0; g8 < 6; ++g8) {
      us8_t pk;
      #pragma unroll
      for (int j = 0; j < 8; ++j) {
        const int colc = seg * 48 + g8 * 8 + j;
        pk[j] = f2bf((v[g8 * 8 + j] - mu) * rs * n1s[colc] + n1b[colc]);
      }
      *reinterpret_cast<us8_t*>(&bA[row * SB + seg * 48 + g8 * 8]) = pk;
    }
  }
  __syncthreads();

  // ---------------- Phase A2: g, c -> packed regs; h1 -> bB ----------------
  f4_t acc[4][2];
  unsigned gp[4][2][2], cp[4][2][2];
  zero_acc(acc);
  gemm_acc<12>(bA, wp + OFF_WG, 0, 24, nw * 2, lane, acc);
  #pragma unroll
  for (int ct = 0; ct < 2; ++ct) {
    const f4_t bgq = *reinterpret_cast<const f4_t*>(&bg[ch0 + ct * 16]);
    #pragma unroll
    for (int pt = 0; pt < 4; ++pt) {
      gp[pt][ct][0] = pack2(fsigmoid(acc[pt][ct][0] + bgq[0]),
                            fsigmoid(acc[pt][ct][1] + bgq[1]));
      gp[pt][ct][1] = pack2(fsigmoid(acc[pt][ct][2] + bgq[2]),
                            fsigmoid(acc[pt][ct][3] + bgq[3]));
    }
  }
  zero_acc(acc);
  gemm_acc<12>(bA, wp + OFF_WU, 0, 24, nw * 2, lane, acc);
  #pragma unroll
  for (int ct = 0; ct < 2; ++ct) {
    const f4_t buq = *reinterpret_cast<const f4_t*>(&bu[ch0 + ct * 16]);
    #pragma unroll
    for (int pt = 0; pt < 4; ++pt) {
      #pragma unroll
      for (int p = 0; p < 2; ++p) {
        const unsigned g = gp[pt][ct][p];
        const float c0 = (1.f - ulo(g)) * (acc[pt][ct][2 * p]     + buq[2 * p]);
        const float c1 = (1.f - uhi(g)) * (acc[pt][ct][2 * p + 1] + buq[2 * p + 1]);
        acc[pt][ct][2 * p] = c0; acc[pt][ct][2 * p + 1] = c1;
        cp[pt][ct][p] = pack2(c0, c1);
      }
    }
  }
  write_tile(bB, acc, ch0, lane);           // h1 = c (bA reads done above)
  __syncthreads();

  // ---------------- Phase B: h' = g*(h@A) + c, ping-pong bB/bA -------------
  {
    unsigned short* cur = bB;
    unsigned short* alt = bA;
    #pragma unroll 1
    for (int stp = 0; stp < 7; ++stp) {     // h2..h8
      zero_acc(acc);
      gemm_acc<12>(cur, wp + OFF_A, 0, 24, nw * 2, lane, acc);
      #pragma unroll
      for (int pt = 0; pt < 4; ++pt)
        #pragma unroll
        for (int ct = 0; ct < 2; ++ct)
          #pragma unroll
          for (int p = 0; p < 2; ++p) {
            const unsigned g = gp[pt][ct][p], c = cp[pt][ct][p];
            acc[pt][ct][2 * p]     = ulo(g) * acc[pt][ct][2 * p]     + ulo(c);
            acc[pt][ct][2 * p + 1] = uhi(g) * acc[pt][ct][2 * p + 1] + uhi(c);
          }
      if (stp < 6) {
        write_tile(alt, acc, ch0, lane);    // write buffer nobody is reading
        unsigned short* t = cur; cur = alt; alt = t;
        __syncthreads();
      }
    }
  }
  // last recurrence reads hit bB (fenced later); bA reads fenced at stp5.

  // ------- Phase C: y = x + h8 -> out (f32 scratch); LN2 -> xn2 in bA ------
  #pragma unroll
  for (int pt = 0; pt < 4; ++pt) {
    const int pix = pt * 16 + pixb;
    float s = 0.f, s2 = 0.f;
    #pragma unroll
    for (int ct = 0; ct < 2; ++ct) {
      const size_t pos = (size_t)(r0 + pix) * CCH + ch0 + ct * 16;
      const f4_t xq = *reinterpret_cast<const f4_t*>(&x[pos]);
      f4_t yq;
      #pragma unroll
      for (int j = 0; j < 4; ++j) {
        const float y = xq[j] + acc[pt][ct][j];
        yq[j] = y; acc[pt][ct][j] = y;
        s += y; s2 += y * y;
      }
      *reinterpret_cast<f4_t*>(&out[pos]) = yq;   // same-thread reread in E
    }
    s += __shfl_xor(s, 16, 64); s2 += __shfl_xor(s2, 16, 64);
    s += __shfl_xor(s, 32, 64); s2 += __shfl_xor(s2, 32, 64);
    if (lane < 16) { part[pix][nw][0] = s; part[pix][nw][1] = s2; }
  }
  __syncthreads();
  if (tid < BMROWS) {
    float s = 0.f, s2 = 0.f;
    #pragma unroll
    for (int w = 0; w < 12; ++w) { s += part[tid][w][0]; s2 += part[tid][w][1]; }
    const float mu = s * (1.f / CCH);
    srow[tid][0] = mu;
    srow[tid][1] = rsqrtf(fmaxf(s2 * (1.f / CCH) - mu * mu, 0.f) + LNEPS);
  }
  __syncthreads();
  {
    f4_t scq[2], bsq[2];
    #pragma unroll
    for (int ct = 0; ct < 2; ++ct) {
      scq[ct] = *reinterpret_cast<const f4_t*>(&n2s[ch0 + ct * 16]);
      bsq[ct] = *reinterpret_cast<const f4_t*>(&n2b[ch0 + ct * 16]);
    }
    #pragma unroll
    for (int pt = 0; pt < 4; ++pt) {
      const int pix = pt * 16 + pixb;
      const float mu = srow[pix][0], rs = srow[pix][1];
      #pragma unroll
      for (int ct = 0; ct < 2; ++ct)
        #pragma unroll
        for (int j = 0; j < 4; ++j)
          acc[pt][ct][j] = (acc[pt][ct][j] - mu) * rs * scq[ct][j] + bsq[ct][j];
    }
    write_tile(bA, acc, ch0, lane);         // xn2 (bA reads fenced at stp5)
  }
  __syncthreads();

  // ------- Phase D: MLP in 4 HID-chunks, m double-buffered bB/bC -----------
  f4_t aco[4][2];
  zero_acc(aco);                            // MFMA-only until E -> AGPR
  #pragma unroll 1
  for (int ch = 0; ch < 4; ++ch) {
    unsigned short* buf = (ch & 1) ? bC : bB;
    zero_acc(acc);
    gemm_acc<12>(bA, wp + OFF_W1, 0, 96, ch * 24 + nw * 2, lane, acc);
    #pragma unroll
    for (int ct = 0; ct < 2; ++ct) {
      const f4_t b1q = *reinterpret_cast<const f4_t*>(&b1[ch * 384 + ch0 + ct * 16]);
      #pragma unroll
      for (int pt = 0; pt < 4; ++pt)
        #pragma unroll
        for (int j = 0; j < 4; ++j) {
          // gelu(z) = z / (1 + 2^(-2.3021178*(z + 0.044715 z^3)))
          const float z = acc[pt][ct][j] + b1q[j];
          const float m = z * z;
          const float t = z * fmaf(m, 0.044715f, 1.0f);
          const float e = exp2f(t * -2.30211774f);
          acc[pt][ct][j] = z * __builtin_amdgcn_rcpf(1.f + e);
        }
    }
    write_tile(buf, acc, ch0, lane);
    __syncthreads();                        // buf complete; prev buf readers
                                            // passed the previous barrier
    gemm_acc<12>(buf, wp + OFF_W2, ch * 12, 24, nw * 2, lane, aco);
  }

  // ---------------- Phase E: out = y + mlp + b2 (same-thread reread) -------
  {
    f4_t b2q[2];
    #pragma unroll
    for (int ct = 0; ct < 2; ++ct)
      b2q[ct] = *reinterpret_cast<const f4_t*>(&b2[ch0 + ct * 16]);
    #pragma unroll
    for (int pt = 0; pt < 4; ++pt) {
      const int pix = pt * 16 + pixb;
      #pragma unroll
      for (int ct = 0; ct < 2; ++ct) {
        const size_t pos = (size_t)(r0 + pix) * CCH + ch0 + ct * 16;
        const f4_t yq = *reinterpret_cast<const f4_t*>(&out[pos]);
        f4_t o;
        #pragma unroll
        for (int j = 0; j < 4; ++j)
          o[j] = yq[j] + aco[pt][ct][j] + b2q[ct][j];
        *reinterpret_cast<f4_t*>(&out[pos]) = o;
      }
    }
  }
}

extern "C" void kernel_launch(void* const* d_in, const int* in_sizes, int n_in,
                              void* d_out, int out_size, void* d_ws, size_t ws_size,
                              hipStream_t stream) {
  const float* x   = (const float*)d_in[0];
  const float* n1s = (const float*)d_in[1];
  const float* n1b = (const float*)d_in[2];
  const float* Wu  = (const float*)d_in[3];
  const float* bu  = (const float*)d_in[4];
  const float* Wg  = (const float*)d_in[5];
  const float* bg  = (const float*)d_in[6];
  const float* A   = (const float*)d_in[7];
  const float* n2s = (const float*)d_in[8];
  const float* n2b = (const float*)d_in[9];
  const float* W1  = (const float*)d_in[10];
  const float* b1  = (const float*)d_in[11];
  const float* W2  = (const float*)d_in[12];
  const float* b2  = (const float*)d_in[13];
  unsigned short* wp = (unsigned short*)d_ws;
  float* out = (float*)d_out;

  // pack all weights to bf16 fragment order (one launch; 3168 tiles * 64 lanes)
  pack_all<<<(3168 * 64) / 256, 256, 0, stream>>>(Wu, Wg, A, W1, W2, wp);

  cssm_main<<<NPIX / BMROWS, NTHR, 0, stream>>>(
      x, n1s, n1b, bu, bg, n2s, n2b, b1, b2, wp, out);
}

// Round 15
// 102.125 us; speedup vs baseline: 2.4006x; 1.0815x over previous
//
#include <hip/hip_runtime.h>
#include <hip/hip_bf16.h>
#include <hip/hip_fp8.h>

// CSSM TinyViT block, fused MFMA implementation for gfx950.
// B=16,H=32,W=32 -> 16384 rows of C=384. T=8, HID=1536.
// Round 15 = round 14 structure (12 waves, disjoint 32-chan slices, zero
// weight duplication) with ALL gemm operands in OCP fp8 e4m3:
// weights pre-scaled x64 at pack time, activations stored x8 in fp8 LDS,
// dequant 1/512 folded into bias/gate ops. Halves the compulsory per-CU
// L2 weight stream (36us -> 18us), LDS bytes, and W-load count.
// mfma_f32_16x16x32_fp8_fp8 (i64 operands), same k-grouping as bf16.

#define CCH   384          // global row stride (elements)
#define SBB   400          // LDS row stride in BYTES: 384 + 16 pad
#define NPIX  16384
#define BMROWS 64          // pixels per block
#define NTHR  768          // 12 waves; wave owns 32 chans x 64 pixels
#define LNEPS 1e-6f
#define HBUF  (BMROWS * SBB)  // 25600 bytes per buffer
#define WSC   64.0f        // weight pre-scale (pack time)
#define ASC   8.0f         // activation scale (LDS store time)
#define DQ    0.001953125f // 1/(WSC*ASC)

typedef __attribute__((ext_vector_type(4))) float f4_t;    // 4 x f32

// workspace offsets (BYTE units). Each 16x16x32 fp8 W-tile = 512 B.
// K-MAJOR tile order: tile = kb * (N/16) + n16   (kb = K/32 block)
#define OFF_WU 0u
#define OFF_WG 147456u      // 288 tiles * 512 B
#define OFF_A  294912u
#define OFF_W1 442368u      // 384x1536 -> 1152 tiles
#define OFF_W2 1032192u     // 1536x384 -> 1152 tiles

__device__ __forceinline__ unsigned char f2e4(float f) {
  __hip_fp8_e4m3 t(f);                       // OCP e4m3fn, HW cvt on gfx950
  return (unsigned char)t.__x;
}
__device__ __forceinline__ unsigned short f2bf(float f) {
  return __builtin_bit_cast(unsigned short, __float2bfloat16(f));
}
__device__ __forceinline__ unsigned pack2(float lo, float hi) {
  return (unsigned)f2bf(lo) | ((unsigned)f2bf(hi) << 16);
}
__device__ __forceinline__ float ulo(unsigned u) {
  union { unsigned x; float f; } v; v.x = u << 16; return v.f;
}
__device__ __forceinline__ float uhi(unsigned u) {
  union { unsigned x; float f; } v; v.x = u & 0xffff0000u; return v.f;
}
// sigmoid(z) = 1/(1+2^(-z*log2e))
__device__ __forceinline__ float fsigmoid(float z) {
  return __builtin_amdgcn_rcpf(1.f + exp2f(z * -1.44269504088896f));
}

// Pack all five f32 weights into fp8 MFMA-A fragment order, k-major tiles:
// P[off + tile*512 + lane*8 + j] = e4m3(WSC * W[kb*32+(lane>>4)*8+j][n16*16+(lane&15)])
__global__ void pack_all(const float* __restrict__ Wu, const float* __restrict__ Wg,
                         const float* __restrict__ A,  const float* __restrict__ W1,
                         const float* __restrict__ W2, unsigned char* __restrict__ P) {
  const int gid = blockIdx.x * blockDim.x + threadIdx.x;
  const int l = gid & 63;
  int tile = gid >> 6;
  const float* W; int N; unsigned off; int t;
  if      (tile <  288) { W = Wu; N = 384;  off = OFF_WU; t = tile;        }
  else if (tile <  576) { W = Wg; N = 384;  off = OFF_WG; t = tile - 288;  }
  else if (tile <  864) { W = A;  N = 384;  off = OFF_A;  t = tile - 576;  }
  else if (tile < 2016) { W = W1; N = 1536; off = OFF_W1; t = tile - 864;  }
  else if (tile < 3168) { W = W2; N = 384;  off = OFF_W2; t = tile - 2016; }
  else return;
  const int ntn = N >> 4;
  const int kb  = t / ntn, n16 = t % ntn;
  const int krow = kb * 32 + ((l >> 4) << 3);
  const int col  = n16 * 16 + (l & 15);
  unsigned long long pk = 0ull;
  #pragma unroll
  for (int j = 0; j < 8; ++j)
    pk |= (unsigned long long)f2e4(W[(size_t)(krow + j) * N + col] * WSC) << (8 * j);
  *reinterpret_cast<unsigned long long*>(P + off + ((size_t)t << 9) + (l << 3)) = pk;
}

// acc[4][2] += W^T(2 chan-tiles, packed fp8) * X^T(LDS fp8, 4 pixel-tiles).
// acc[pt][ct]: D[chan][pix]; lane holds 4 consecutive chans of pixel
// pt*16 + (lane&15). Raw output = (ASC*x)@(WSC*w) -> caller applies DQ.
template <int NKB>
__device__ __forceinline__ void gemm_acc(const unsigned char* sb,
                                         const unsigned char* __restrict__ wt,
                                         int kb0, int ntn, int n16base,
                                         int lane, f4_t acc[4][2]) {
  const int r    = lane & 15;
  const int koff = (lane >> 4) << 3;        // byte offset of 8-k group
  __builtin_amdgcn_s_setprio(1);
  #pragma unroll 4
  for (int kb = 0; kb < NKB; ++kb) {
    const int ac = kb * 32 + koff;          // 32 bytes per k-block
    long long p[4];
    #pragma unroll
    for (int pt = 0; pt < 4; ++pt)
      p[pt] = *reinterpret_cast<const long long*>(&sb[(pt * 16 + r) * SBB + ac]);
    const unsigned char* bt =
        wt + (((size_t)((kb0 + kb) * ntn + n16base)) << 9) + (lane << 3);
    #pragma unroll
    for (int ct = 0; ct < 2; ++ct) {
      const long long w = *reinterpret_cast<const long long*>(bt + (ct << 9));
      #pragma unroll
      for (int pt = 0; pt < 4; ++pt)
        acc[pt][ct] = __builtin_amdgcn_mfma_f32_16x16x32_fp8_fp8(w, p[pt], acc[pt][ct], 0, 0, 0);
    }
  }
  __builtin_amdgcn_s_setprio(0);
}

// write C/D tile (unscaled values) into fp8 LDS [pix][chan] buffer, x ASC:
// each (pt,ct) quad = 4 consecutive chans of one pixel -> one ds_write_b32.
__device__ __forceinline__ void write_tile(unsigned char* sb, const f4_t t[4][2],
                                           int ch0, int lane) {
  const int pixb = lane & 15;
  #pragma unroll
  for (int pt = 0; pt < 4; ++pt) {
    const int pix = pt * 16 + pixb;
    #pragma unroll
    for (int ct = 0; ct < 2; ++ct) {
      const unsigned v = (unsigned)f2e4(t[pt][ct][0] * ASC)
                       | ((unsigned)f2e4(t[pt][ct][1] * ASC) << 8)
                       | ((unsigned)f2e4(t[pt][ct][2] * ASC) << 16)
                       | ((unsigned)f2e4(t[pt][ct][3] * ASC) << 24);
      *reinterpret_cast<unsigned*>(&sb[pix * SBB + ch0 + ct * 16]) = v;
    }
  }
}

__device__ __forceinline__ void zero_acc(f4_t a[4][2]) {
  #pragma unroll
  for (int pt = 0; pt < 4; ++pt)
    #pragma unroll
    for (int ct = 0; ct < 2; ++ct) a[pt][ct] = (f4_t){0.f, 0.f, 0.f, 0.f};
}

__global__ __launch_bounds__(NTHR, 1) void cssm_main(
    const float* __restrict__ x,
    const float* __restrict__ n1s, const float* __restrict__ n1b,
    const float* __restrict__ bu, const float* __restrict__ bg,
    const float* __restrict__ n2s, const float* __restrict__ n2b,
    const float* __restrict__ b1, const float* __restrict__ b2,
    const unsigned char* __restrict__ wp,
    float* __restrict__ out) {
  __shared__ unsigned char sm[3 * HBUF];    // bA | bB | bC (25.6KB each)
  __shared__ float part[BMROWS][12][2];     // per-(pixel,chan-slot) LN2 partials
  __shared__ float srow[BMROWS][2];         // LN2 mu, rs per pixel
  unsigned char* bA = sm;                   // xn -> h ping -> xn2
  unsigned char* bB = sm + HBUF;            // h pong -> m even chunks
  unsigned char* bC = sm + 2 * HBUF;        // m odd chunks

  const int tid = threadIdx.x;
  const int lane = tid & 63;
  const int nw = tid >> 6;                  // chan-slot 0..11: chans nw*32..+31
  const int r0 = blockIdx.x * BMROWS;
  const int pixb = lane & 15;
  const int ch0  = nw * 32 + ((lane >> 4) << 2);   // byte == chan index

  // ---------------- Phase A: LN1(x) -> bA (fp8 x ASC) ----------------------
  if (tid < 512) {
    const int row = tid >> 3, seg = tid & 7;     // 8 thr/row, 48 elems each
    const float* xr = x + (size_t)(r0 + row) * CCH + seg * 48;
    float v[48];
    float s = 0.f, s2 = 0.f;
    #pragma unroll
    for (int i = 0; i < 12; ++i) {
      const f4_t t = reinterpret_cast<const f4_t*>(xr)[i];
      #pragma unroll
      for (int j = 0; j < 4; ++j) { const float f = t[j]; v[i * 4 + j] = f; s += f; s2 += f * f; }
    }
    #pragma unroll
    for (int o = 1; o < 8; o <<= 1) { s += __shfl_xor(s, o, 64); s2 += __shfl_xor(s2, o, 64); }
    const float mu = s * (1.f / CCH);
    const float rs = rsqrtf(fmaxf(s2 * (1.f / CCH) - mu * mu, 0.f) + LNEPS);
    #pragma unroll
    for (int g8 = 0; g8 < 6; ++g8) {
      unsigned long long pk = 0ull;
      #pragma unroll
      for (int j = 0; j < 8; ++j) {
        const int colc = seg * 48 + g8 * 8 + j;
        pk |= (unsigned long long)f2e4(((v[g8 * 8 + j] - mu) * rs * n1s[colc] + n1b[colc]) * ASC)
              << (8 * j);
      }
      *reinterpret_cast<unsigned long long*>(&bA[row * SBB + seg * 48 + g8 * 8]) = pk;
    }
  }
  __syncthreads();

  // ---------------- Phase A2: g, c -> packed regs; h1 -> bB ----------------
  f4_t acc[4][2];
  unsigned gp[4][2][2], cp[4][2][2];
  zero_acc(acc);
  gemm_acc<12>(bA, wp + OFF_WG, 0, 24, nw * 2, lane, acc);
  #pragma unroll
  for (int ct = 0; ct < 2; ++ct) {
    const f4_t bgq = *reinterpret_cast<const f4_t*>(&bg[ch0 + ct * 16]);
    #pragma unroll
    for (int pt = 0; pt < 4; ++pt) {
      gp[pt][ct][0] = pack2(fsigmoid(acc[pt][ct][0] * DQ + bgq[0]),
                            fsigmoid(acc[pt][ct][1] * DQ + bgq[1]));
      gp[pt][ct][1] = pack2(fsigmoid(acc[pt][ct][2] * DQ + bgq[2]),
                            fsigmoid(acc[pt][ct][3] * DQ + bgq[3]));
    }
  }
  zero_acc(acc);
  gemm_acc<12>(bA, wp + OFF_WU, 0, 24, nw * 2, lane, acc);
  #pragma unroll
  for (int ct = 0; ct < 2; ++ct) {
    const f4_t buq = *reinterpret_cast<const f4_t*>(&bu[ch0 + ct * 16]);
    #pragma unroll
    for (int pt = 0; pt < 4; ++pt) {
      #pragma unroll
      for (int p = 0; p < 2; ++p) {
        const unsigned g = gp[pt][ct][p];
        const float c0 = (1.f - ulo(g)) * (acc[pt][ct][2 * p]     * DQ + buq[2 * p]);
        const float c1 = (1.f - uhi(g)) * (acc[pt][ct][2 * p + 1] * DQ + buq[2 * p + 1]);
        acc[pt][ct][2 * p] = c0; acc[pt][ct][2 * p + 1] = c1;
        cp[pt][ct][p] = pack2(c0, c1);
      }
    }
  }
  write_tile(bB, acc, ch0, lane);           // h1 = c (bA reads done above)
  __syncthreads();

  // ---------------- Phase B: h' = g*(DQ*(h@A)) + c, ping-pong bB/bA --------
  {
    unsigned char* cur = bB;
    unsigned char* alt = bA;
    #pragma unroll 1
    for (int stp = 0; stp < 7; ++stp) {     // h2..h8
      zero_acc(acc);
      gemm_acc<12>(cur, wp + OFF_A, 0, 24, nw * 2, lane, acc);
      #pragma unroll
      for (int pt = 0; pt < 4; ++pt)
        #pragma unroll
        for (int ct = 0; ct < 2; ++ct)
          #pragma unroll
          for (int p = 0; p < 2; ++p) {
            const unsigned g = gp[pt][ct][p], c = cp[pt][ct][p];
            acc[pt][ct][2 * p]     = ulo(g) * (acc[pt][ct][2 * p]     * DQ) + ulo(c);
            acc[pt][ct][2 * p + 1] = uhi(g) * (acc[pt][ct][2 * p + 1] * DQ) + uhi(c);
          }
      if (stp < 6) {
        write_tile(alt, acc, ch0, lane);    // write buffer nobody is reading
        unsigned char* t = cur; cur = alt; alt = t;
        __syncthreads();
      }
    }
  }
  // last recurrence reads hit bB (fenced later); bA reads fenced at stp5.

  // ------- Phase C: y = x + h8 -> out (f32 scratch); LN2 -> xn2 in bA ------
  #pragma unroll
  for (int pt = 0; pt < 4; ++pt) {
    const int pix = pt * 16 + pixb;
    float s = 0.f, s2 = 0.f;
    #pragma unroll
    for (int ct = 0; ct < 2; ++ct) {
      const size_t pos = (size_t)(r0 + pix) * CCH + ch0 + ct * 16;
      const f4_t xq = *reinterpret_cast<const f4_t*>(&x[pos]);
      f4_t yq;
      #pragma unroll
      for (int j = 0; j < 4; ++j) {
        const float y = xq[j] + acc[pt][ct][j];
        yq[j] = y; acc[pt][ct][j] = y;
        s += y; s2 += y * y;
      }
      *reinterpret_cast<f4_t*>(&out[pos]) = yq;   // same-thread reread in E
    }
    s += __shfl_xor(s, 16, 64); s2 += __shfl_xor(s2, 16, 64);
    s += __shfl_xor(s, 32, 64); s2 += __shfl_xor(s2, 32, 64);
    if (lane < 16) { part[pix][nw][0] = s; part[pix][nw][1] = s2; }
  }
  __syncthreads();
  if (tid < BMROWS) {
    float s = 0.f, s2 = 0.f;
    #pragma unroll
    for (int w = 0; w < 12; ++w) { s += part[tid][w][0]; s2 += part[tid][w][1]; }
    const float mu = s * (1.f / CCH);
    srow[tid][0] = mu;
    srow[tid][1] = rsqrtf(fmaxf(s2 * (1.f / CCH) - mu * mu, 0.f) + LNEPS);
  }
  __syncthreads();
  {
    f4_t scq[2], bsq[2];
    #pragma unroll
    for (int ct = 0; ct < 2; ++ct) {
      scq[ct] = *reinterpret_cast<const f4_t*>(&n2s[ch0 + ct * 16]);
      bsq[ct] = *reinterpret_cast<const f4_t*>(&n2b[ch0 + ct * 16]);
    }
    #pragma unroll
    for (int pt = 0; pt < 4; ++pt) {
      const int pix = pt * 16 + pixb;
      const float mu = srow[pix][0], rs = srow[pix][1];
      #pragma unroll
      for (int ct = 0; ct < 2; ++ct)
        #pragma unroll
        for (int j = 0; j < 4; ++j)
          acc[pt][ct][j] = (acc[pt][ct][j] - mu) * rs * scq[ct][j] + bsq[ct][j];
    }
    write_tile(bA, acc, ch0, lane);         // xn2 (bA reads fenced at stp5)
  }
  __syncthreads();

  // ------- Phase D: MLP in 4 HID-chunks, m double-buffered bB/bC -----------
  f4_t aco[4][2];
  zero_acc(aco);                            // MFMA-only until E -> AGPR
  #pragma unroll 1
  for (int ch = 0; ch < 4; ++ch) {
    unsigned char* buf = (ch & 1) ? bC : bB;
    zero_acc(acc);
    gemm_acc<12>(bA, wp + OFF_W1, 0, 96, ch * 24 + nw * 2, lane, acc);
    #pragma unroll
    for (int ct = 0; ct < 2; ++ct) {
      const f4_t b1q = *reinterpret_cast<const f4_t*>(&b1[ch * 384 + ch0 + ct * 16]);
      #pragma unroll
      for (int pt = 0; pt < 4; ++pt)
        #pragma unroll
        for (int j = 0; j < 4; ++j) {
          // gelu(z) = z / (1 + 2^(-2.3021178*(z + 0.044715 z^3)))
          const float z = acc[pt][ct][j] * DQ + b1q[j];
          const float m = z * z;
          const float t = z * fmaf(m, 0.044715f, 1.0f);
          const float e = exp2f(t * -2.30211774f);
          acc[pt][ct][j] = z * __builtin_amdgcn_rcpf(1.f + e);
        }
    }
    write_tile(buf, acc, ch0, lane);
    __syncthreads();                        // buf complete; prev buf readers
                                            // passed the previous barrier
    gemm_acc<12>(buf, wp + OFF_W2, ch * 12, 24, nw * 2, lane, aco);
  }

  // ---------------- Phase E: out = y + DQ*mlp + b2 (same-thread reread) ----
  {
    f4_t b2q[2];
    #pragma unroll
    for (int ct = 0; ct < 2; ++ct)
      b2q[ct] = *reinterpret_cast<const f4_t*>(&b2[ch0 + ct * 16]);
    #pragma unroll
    for (int pt = 0; pt < 4; ++pt) {
      const int pix = pt * 16 + pixb;
      #pragma unroll
      for (int ct = 0; ct < 2; ++ct) {
        const size_t pos = (size_t)(r0 + pix) * CCH + ch0 + ct * 16;
        const f4_t yq = *reinterpret_cast<const f4_t*>(&out[pos]);
        f4_t o;
        #pragma unroll
        for (int j = 0; j < 4; ++j)
          o[j] = yq[j] + aco[pt][ct][j] * DQ + b2q[ct][j];
        *reinterpret_cast<f4_t*>(&out[pos]) = o;
      }
    }
  }
}

extern "C" void kernel_launch(void* const* d_in, const int* in_sizes, int n_in,
                              void* d_out, int out_size, void* d_ws, size_t ws_size,
                              hipStream_t stream) {
  const float* x   = (const float*)d_in[0];
  const float* n1s = (const float*)d_in[1];
  const float* n1b = (const float*)d_in[2];
  const float* Wu  = (const float*)d_in[3];
  const float* bu  = (const float*)d_in[4];
  const float* Wg  = (const float*)d_in[5];
  const float* bg  = (const float*)d_in[6];
  const float* A   = (const float*)d_in[7];
  const float* n2s = (const float*)d_in[8];
  const float* n2b = (const float*)d_in[9];
  const float* W1  = (const float*)d_in[10];
  const float* b1  = (const float*)d_in[11];
  const float* W2  = (const float*)d_in[12];
  const float* b2  = (const float*)d_in[13];
  unsigned char* wp = (unsigned char*)d_ws;
  float* out = (float*)d_out;

  // pack all weights to fp8 fragment order (one launch; 3168 tiles * 64 lanes)
  pack_all<<<(3168 * 64) / 256, 256, 0, stream>>>(Wu, Wg, A, W1, W2, wp);

  cssm_main<<<NPIX / BMROWS, NTHR, 0, stream>>>(
      x, n1s, n1b, bu, bg, n2s, n2b, b1, b2, wp, out);
}

// Round 16
// 91.578 us; speedup vs baseline: 2.6770x; 1.1152x over previous
//
#include <hip/hip_runtime.h>
#include <hip/hip_bf16.h>
#include <hip/hip_fp8.h>

// CSSM TinyViT block, fused MFMA implementation for gfx950.
// B=16,H=32,W=32 -> 16384 rows of C=384. T=8, HID=1536.
// Round 16 = round 15 (fp8 operands, 12 waves, disjoint chan slices) +
//  (1) SBB 400->392: gemm b64 LDS reads go 8-way -> ~2-way bank mapping,
//  (2) v_cvt_pk_fp8_f32 packed converts in write_tile/LN stores,
//  (3) DQ folded into gate after c (recurrence back to 2-op fma).

#define CCH   384          // global row stride (elements)
#define SBB   392          // LDS row stride in BYTES: 384 + 8 pad (98 dwords)
#define NPIX  16384
#define BMROWS 64          // pixels per block
#define NTHR  768          // 12 waves; wave owns 32 chans x 64 pixels
#define LNEPS 1e-6f
#define HBUF  (BMROWS * SBB)  // 25088 bytes per buffer
#define WSC   64.0f        // weight pre-scale (pack time)
#define ASC   8.0f         // activation scale (LDS store time)
#define DQ    0.001953125f // 1/(WSC*ASC)

typedef __attribute__((ext_vector_type(4))) float f4_t;    // 4 x f32

// workspace offsets (BYTE units). Each 16x16x32 fp8 W-tile = 512 B.
// K-MAJOR tile order: tile = kb * (N/16) + n16   (kb = K/32 block)
#define OFF_WU 0u
#define OFF_WG 147456u      // 288 tiles * 512 B
#define OFF_A  294912u
#define OFF_W1 442368u      // 384x1536 -> 1152 tiles
#define OFF_W2 1032192u     // 1536x384 -> 1152 tiles

__device__ __forceinline__ unsigned char f2e4(float f) {
  __hip_fp8_e4m3 t(f);                       // OCP e4m3fn, HW cvt on gfx950
  return (unsigned char)t.__x;
}

#if __has_builtin(__builtin_amdgcn_cvt_pk_fp8_f32)
// pack 4 f32 (pre-scaled) into 4 fp8 bytes with 2 HW packed converts
__device__ __forceinline__ unsigned pk4e4(float a, float b, float c, float d) {
  int v = __builtin_amdgcn_cvt_pk_fp8_f32(a, b, 0, false);
  v = __builtin_amdgcn_cvt_pk_fp8_f32(c, d, v, true);
  return (unsigned)v;
}
#else
__device__ __forceinline__ unsigned pk4e4(float a, float b, float c, float d) {
  return (unsigned)f2e4(a) | ((unsigned)f2e4(b) << 8)
       | ((unsigned)f2e4(c) << 16) | ((unsigned)f2e4(d) << 24);
}
#endif

__device__ __forceinline__ unsigned short f2bf(float f) {
  return __builtin_bit_cast(unsigned short, __float2bfloat16(f));
}
__device__ __forceinline__ unsigned pack2(float lo, float hi) {
  return (unsigned)f2bf(lo) | ((unsigned)f2bf(hi) << 16);
}
__device__ __forceinline__ float ulo(unsigned u) {
  union { unsigned x; float f; } v; v.x = u << 16; return v.f;
}
__device__ __forceinline__ float uhi(unsigned u) {
  union { unsigned x; float f; } v; v.x = u & 0xffff0000u; return v.f;
}
// sigmoid(z) = 1/(1+2^(-z*log2e))
__device__ __forceinline__ float fsigmoid(float z) {
  return __builtin_amdgcn_rcpf(1.f + exp2f(z * -1.44269504088896f));
}

// Pack all five f32 weights into fp8 MFMA-A fragment order, k-major tiles:
// P[off + tile*512 + lane*8 + j] = e4m3(WSC * W[kb*32+(lane>>4)*8+j][n16*16+(lane&15)])
__global__ void pack_all(const float* __restrict__ Wu, const float* __restrict__ Wg,
                         const float* __restrict__ A,  const float* __restrict__ W1,
                         const float* __restrict__ W2, unsigned char* __restrict__ P) {
  const int gid = blockIdx.x * blockDim.x + threadIdx.x;
  const int l = gid & 63;
  int tile = gid >> 6;
  const float* W; int N; unsigned off; int t;
  if      (tile <  288) { W = Wu; N = 384;  off = OFF_WU; t = tile;        }
  else if (tile <  576) { W = Wg; N = 384;  off = OFF_WG; t = tile - 288;  }
  else if (tile <  864) { W = A;  N = 384;  off = OFF_A;  t = tile - 576;  }
  else if (tile < 2016) { W = W1; N = 1536; off = OFF_W1; t = tile - 864;  }
  else if (tile < 3168) { W = W2; N = 384;  off = OFF_W2; t = tile - 2016; }
  else return;
  const int ntn = N >> 4;
  const int kb  = t / ntn, n16 = t % ntn;
  const int krow = kb * 32 + ((l >> 4) << 3);
  const int col  = n16 * 16 + (l & 15);
  unsigned long long pk = 0ull;
  #pragma unroll
  for (int j = 0; j < 8; ++j)
    pk |= (unsigned long long)f2e4(W[(size_t)(krow + j) * N + col] * WSC) << (8 * j);
  *reinterpret_cast<unsigned long long*>(P + off + ((size_t)t << 9) + (l << 3)) = pk;
}

// acc[4][2] += W^T(2 chan-tiles, packed fp8) * X^T(LDS fp8, 4 pixel-tiles).
// acc[pt][ct]: D[chan][pix]; lane holds 4 consecutive chans of pixel
// pt*16 + (lane&15). Raw output = (ASC*x)@(WSC*w) -> caller applies DQ.
template <int NKB>
__device__ __forceinline__ void gemm_acc(const unsigned char* sb,
                                         const unsigned char* __restrict__ wt,
                                         int kb0, int ntn, int n16base,
                                         int lane, f4_t acc[4][2]) {
  const int r    = lane & 15;
  const int koff = (lane >> 4) << 3;        // byte offset of 8-k group
  __builtin_amdgcn_s_setprio(1);
  #pragma unroll 4
  for (int kb = 0; kb < NKB; ++kb) {
    const int ac = kb * 32 + koff;          // 32 bytes per k-block
    long long p[4];
    #pragma unroll
    for (int pt = 0; pt < 4; ++pt)
      p[pt] = *reinterpret_cast<const long long*>(&sb[(pt * 16 + r) * SBB + ac]);
    const unsigned char* bt =
        wt + (((size_t)((kb0 + kb) * ntn + n16base)) << 9) + (lane << 3);
    #pragma unroll
    for (int ct = 0; ct < 2; ++ct) {
      const long long w = *reinterpret_cast<const long long*>(bt + (ct << 9));
      #pragma unroll
      for (int pt = 0; pt < 4; ++pt)
        acc[pt][ct] = __builtin_amdgcn_mfma_f32_16x16x32_fp8_fp8(w, p[pt], acc[pt][ct], 0, 0, 0);
    }
  }
  __builtin_amdgcn_s_setprio(0);
}

// write C/D tile (unscaled values) into fp8 LDS [pix][chan] buffer, x ASC:
// each (pt,ct) quad -> one pk4e4 (2 HW cvts) + one ds_write_b32.
__device__ __forceinline__ void write_tile(unsigned char* sb, const f4_t t[4][2],
                                           int ch0, int lane) {
  const int pixb = lane & 15;
  #pragma unroll
  for (int pt = 0; pt < 4; ++pt) {
    const int pix = pt * 16 + pixb;
    #pragma unroll
    for (int ct = 0; ct < 2; ++ct) {
      const unsigned v = pk4e4(t[pt][ct][0] * ASC, t[pt][ct][1] * ASC,
                               t[pt][ct][2] * ASC, t[pt][ct][3] * ASC);
      *reinterpret_cast<unsigned*>(&sb[pix * SBB + ch0 + ct * 16]) = v;
    }
  }
}

__device__ __forceinline__ void zero_acc(f4_t a[4][2]) {
  #pragma unroll
  for (int pt = 0; pt < 4; ++pt)
    #pragma unroll
    for (int ct = 0; ct < 2; ++ct) a[pt][ct] = (f4_t){0.f, 0.f, 0.f, 0.f};
}

__global__ __launch_bounds__(NTHR, 1) void cssm_main(
    const float* __restrict__ x,
    const float* __restrict__ n1s, const float* __restrict__ n1b,
    const float* __restrict__ bu, const float* __restrict__ bg,
    const float* __restrict__ n2s, const float* __restrict__ n2b,
    const float* __restrict__ b1, const float* __restrict__ b2,
    const unsigned char* __restrict__ wp,
    float* __restrict__ out) {
  __shared__ unsigned char sm[3 * HBUF];    // bA | bB | bC (24.5KB each)
  __shared__ float part[BMROWS][12][2];     // per-(pixel,chan-slot) LN2 partials
  __shared__ float srow[BMROWS][2];         // LN2 mu, rs per pixel
  unsigned char* bA = sm;                   // xn -> h ping -> xn2
  unsigned char* bB = sm + HBUF;            // h pong -> m even chunks
  unsigned char* bC = sm + 2 * HBUF;        // m odd chunks

  const int tid = threadIdx.x;
  const int lane = tid & 63;
  const int nw = tid >> 6;                  // chan-slot 0..11: chans nw*32..+31
  const int r0 = blockIdx.x * BMROWS;
  const int pixb = lane & 15;
  const int ch0  = nw * 32 + ((lane >> 4) << 2);   // byte == chan index

  // ---------------- Phase A: LN1(x) -> bA (fp8 x ASC) ----------------------
  if (tid < 512) {
    const int row = tid >> 3, seg = tid & 7;     // 8 thr/row, 48 elems each
    const float* xr = x + (size_t)(r0 + row) * CCH + seg * 48;
    float v[48];
    float s = 0.f, s2 = 0.f;
    #pragma unroll
    for (int i = 0; i < 12; ++i) {
      const f4_t t = reinterpret_cast<const f4_t*>(xr)[i];
      #pragma unroll
      for (int j = 0; j < 4; ++j) { const float f = t[j]; v[i * 4 + j] = f; s += f; s2 += f * f; }
    }
    #pragma unroll
    for (int o = 1; o < 8; o <<= 1) { s += __shfl_xor(s, o, 64); s2 += __shfl_xor(s2, o, 64); }
    const float mu = s * (1.f / CCH);
    const float rs = rsqrtf(fmaxf(s2 * (1.f / CCH) - mu * mu, 0.f) + LNEPS);
    #pragma unroll
    for (int g8 = 0; g8 < 6; ++g8) {
      float w[8];
      #pragma unroll
      for (int j = 0; j < 8; ++j) {
        const int colc = seg * 48 + g8 * 8 + j;
        w[j] = ((v[g8 * 8 + j] - mu) * rs * n1s[colc] + n1b[colc]) * ASC;
      }
      uint2 pk;
      pk.x = pk4e4(w[0], w[1], w[2], w[3]);
      pk.y = pk4e4(w[4], w[5], w[6], w[7]);
      *reinterpret_cast<uint2*>(&bA[row * SBB + seg * 48 + g8 * 8]) = pk;
    }
  }
  __syncthreads();

  // ---------------- Phase A2: g, c -> packed regs; h1 -> bB ----------------
  f4_t acc[4][2];
  unsigned gp[4][2][2], cp[4][2][2];
  zero_acc(acc);
  gemm_acc<12>(bA, wp + OFF_WG, 0, 24, nw * 2, lane, acc);
  #pragma unroll
  for (int ct = 0; ct < 2; ++ct) {
    const f4_t bgq = *reinterpret_cast<const f4_t*>(&bg[ch0 + ct * 16]);
    #pragma unroll
    for (int pt = 0; pt < 4; ++pt) {
      gp[pt][ct][0] = pack2(fsigmoid(acc[pt][ct][0] * DQ + bgq[0]),
                            fsigmoid(acc[pt][ct][1] * DQ + bgq[1]));
      gp[pt][ct][1] = pack2(fsigmoid(acc[pt][ct][2] * DQ + bgq[2]),
                            fsigmoid(acc[pt][ct][3] * DQ + bgq[3]));
    }
  }
  zero_acc(acc);
  gemm_acc<12>(bA, wp + OFF_WU, 0, 24, nw * 2, lane, acc);
  #pragma unroll
  for (int ct = 0; ct < 2; ++ct) {
    const f4_t buq = *reinterpret_cast<const f4_t*>(&bu[ch0 + ct * 16]);
    #pragma unroll
    for (int pt = 0; pt < 4; ++pt) {
      #pragma unroll
      for (int p = 0; p < 2; ++p) {
        const unsigned g = gp[pt][ct][p];
        const float c0 = (1.f - ulo(g)) * (acc[pt][ct][2 * p]     * DQ + buq[2 * p]);
        const float c1 = (1.f - uhi(g)) * (acc[pt][ct][2 * p + 1] * DQ + buq[2 * p + 1]);
        acc[pt][ct][2 * p] = c0; acc[pt][ct][2 * p + 1] = c1;
        cp[pt][ct][p] = pack2(c0, c1);
        // fold DQ into the gate for the recurrence: g' = g*DQ (bf16)
        gp[pt][ct][p] = pack2(ulo(g) * DQ, uhi(g) * DQ);
      }
    }
  }
  write_tile(bB, acc, ch0, lane);           // h1 = c (bA reads done above)
  __syncthreads();

  // ---------------- Phase B: h' = g'*(h@A) + c, ping-pong bB/bA ------------
  {
    unsigned char* cur = bB;
    unsigned char* alt = bA;
    #pragma unroll 1
    for (int stp = 0; stp < 7; ++stp) {     // h2..h8
      zero_acc(acc);
      gemm_acc<12>(cur, wp + OFF_A, 0, 24, nw * 2, lane, acc);
      #pragma unroll
      for (int pt = 0; pt < 4; ++pt)
        #pragma unroll
        for (int ct = 0; ct < 2; ++ct)
          #pragma unroll
          for (int p = 0; p < 2; ++p) {
            const unsigned g = gp[pt][ct][p], c = cp[pt][ct][p];
            acc[pt][ct][2 * p]     = ulo(g) * acc[pt][ct][2 * p]     + ulo(c);
            acc[pt][ct][2 * p + 1] = uhi(g) * acc[pt][ct][2 * p + 1] + uhi(c);
          }
      if (stp < 6) {
        write_tile(alt, acc, ch0, lane);    // write buffer nobody is reading
        unsigned char* t = cur; cur = alt; alt = t;
        __syncthreads();
      }
    }
  }
  // last recurrence reads hit bB (fenced later); bA reads fenced at stp5.

  // ------- Phase C: y = x + h8 -> out (f32 scratch); LN2 -> xn2 in bA ------
  #pragma unroll
  for (int pt = 0; pt < 4; ++pt) {
    const int pix = pt * 16 + pixb;
    float s = 0.f, s2 = 0.f;
    #pragma unroll
    for (int ct = 0; ct < 2; ++ct) {
      const size_t pos = (size_t)(r0 + pix) * CCH + ch0 + ct * 16;
      const f4_t xq = *reinterpret_cast<const f4_t*>(&x[pos]);
      f4_t yq;
      #pragma unroll
      for (int j = 0; j < 4; ++j) {
        const float y = xq[j] + acc[pt][ct][j];
        yq[j] = y; acc[pt][ct][j] = y;
        s += y; s2 += y * y;
      }
      *reinterpret_cast<f4_t*>(&out[pos]) = yq;   // same-thread reread in E
    }
    s += __shfl_xor(s, 16, 64); s2 += __shfl_xor(s2, 16, 64);
    s += __shfl_xor(s, 32, 64); s2 += __shfl_xor(s2, 32, 64);
    if (lane < 16) { part[pix][nw][0] = s; part[pix][nw][1] = s2; }
  }
  __syncthreads();
  if (tid < BMROWS) {
    float s = 0.f, s2 = 0.f;
    #pragma unroll
    for (int w = 0; w < 12; ++w) { s += part[tid][w][0]; s2 += part[tid][w][1]; }
    const float mu = s * (1.f / CCH);
    srow[tid][0] = mu;
    srow[tid][1] = rsqrtf(fmaxf(s2 * (1.f / CCH) - mu * mu, 0.f) + LNEPS);
  }
  __syncthreads();
  {
    f4_t scq[2], bsq[2];
    #pragma unroll
    for (int ct = 0; ct < 2; ++ct) {
      scq[ct] = *reinterpret_cast<const f4_t*>(&n2s[ch0 + ct * 16]);
      bsq[ct] = *reinterpret_cast<const f4_t*>(&n2b[ch0 + ct * 16]);
    }
    #pragma unroll
    for (int pt = 0; pt < 4; ++pt) {
      const int pix = pt * 16 + pixb;
      const float mu = srow[pix][0], rs = srow[pix][1];
      #pragma unroll
      for (int ct = 0; ct < 2; ++ct)
        #pragma unroll
        for (int j = 0; j < 4; ++j)
          acc[pt][ct][j] = (acc[pt][ct][j] - mu) * rs * scq[ct][j] + bsq[ct][j];
    }
    write_tile(bA, acc, ch0, lane);         // xn2 (bA reads fenced at stp5)
  }
  __syncthreads();

  // ------- Phase D: MLP in 4 HID-chunks, m double-buffered bB/bC -----------
  f4_t aco[4][2];
  zero_acc(aco);                            // MFMA-only until E -> AGPR
  #pragma unroll 1
  for (int ch = 0; ch < 4; ++ch) {
    unsigned char* buf = (ch & 1) ? bC : bB;
    zero_acc(acc);
    gemm_acc<12>(bA, wp + OFF_W1, 0, 96, ch * 24 + nw * 2, lane, acc);
    #pragma unroll
    for (int ct = 0; ct < 2; ++ct) {
      const f4_t b1q = *reinterpret_cast<const f4_t*>(&b1[ch * 384 + ch0 + ct * 16]);
      #pragma unroll
      for (int pt = 0; pt < 4; ++pt)
        #pragma unroll
        for (int j = 0; j < 4; ++j) {
          // gelu(z) = z / (1 + 2^(-2.3021178*(z + 0.044715 z^3)))
          const float z = acc[pt][ct][j] * DQ + b1q[j];
          const float m = z * z;
          const float t = z * fmaf(m, 0.044715f, 1.0f);
          const float e = exp2f(t * -2.30211774f);
          acc[pt][ct][j] = z * __builtin_amdgcn_rcpf(1.f + e);
        }
    }
    write_tile(buf, acc, ch0, lane);
    __syncthreads();                        // buf complete; prev buf readers
                                            // passed the previous barrier
    gemm_acc<12>(buf, wp + OFF_W2, ch * 12, 24, nw * 2, lane, aco);
  }

  // ---------------- Phase E: out = y + DQ*mlp + b2 (same-thread reread) ----
  {
    f4_t b2q[2];
    #pragma unroll
    for (int ct = 0; ct < 2; ++ct)
      b2q[ct] = *reinterpret_cast<const f4_t*>(&b2[ch0 + ct * 16]);
    #pragma unroll
    for (int pt = 0; pt < 4; ++pt) {
      const int pix = pt * 16 + pixb;
      #pragma unroll
      for (int ct = 0; ct < 2; ++ct) {
        const size_t pos = (size_t)(r0 + pix) * CCH + ch0 + ct * 16;
        const f4_t yq = *reinterpret_cast<const f4_t*>(&out[pos]);
        f4_t o;
        #pragma unroll
        for (int j = 0; j < 4; ++j)
          o[j] = yq[j] + aco[pt][ct][j] * DQ + b2q[ct][j];
        *reinterpret_cast<f4_t*>(&out[pos]) = o;
      }
    }
  }
}

extern "C" void kernel_launch(void* const* d_in, const int* in_sizes, int n_in,
                              void* d_out, int out_size, void* d_ws, size_t ws_size,
                              hipStream_t stream) {
  const float* x   = (const float*)d_in[0];
  const float* n1s = (const float*)d_in[1];
  const float* n1b = (const float*)d_in[2];
  const float* Wu  = (const float*)d_in[3];
  const float* bu  = (const float*)d_in[4];
  const float* Wg  = (const float*)d_in[5];
  const float* bg  = (const float*)d_in[6];
  const float* A   = (const float*)d_in[7];
  const float* n2s = (const float*)d_in[8];
  const float* n2b = (const float*)d_in[9];
  const float* W1  = (const float*)d_in[10];
  const float* b1  = (const float*)d_in[11];
  const float* W2  = (const float*)d_in[12];
  const float* b2  = (const float*)d_in[13];
  unsigned char* wp = (unsigned char*)d_ws;
  float* out = (float*)d_out;

  // pack all weights to fp8 fragment order (one launch; 3168 tiles * 64 lanes)
  pack_all<<<(3168 * 64) / 256, 256, 0, stream>>>(Wu, Wg, A, W1, W2, wp);

  cssm_main<<<NPIX / BMROWS, NTHR, 0, stream>>>(
      x, n1s, n1b, bu, bg, n2s, n2b, b1, b2, wp, out);
}

// Round 17
// 76.099 us; speedup vs baseline: 3.2216x; 1.2034x over previous
//
#include <hip/hip_runtime.h>
#include <hip/hip_bf16.h>
#include <hip/hip_fp8.h>

// CSSM TinyViT block, fused MFMA implementation for gfx950.
// B=16,H=32,W=32 -> 16384 rows of C=384. T=8, HID=1536.
// Round 17 = round 16 + MX-scaled fp8 MFMA (mfma_scale_f32_16x16x128_f8f6f4,
// scales pinned to E8M0=127 i.e. 1.0 -> numerically identical to plain fp8,
// but 2.28x the MFMA rate and 4x fewer MFMA instructions). Weights repacked
// to K=128 tiles (2048B, 32B/lane); LDS stride 400B for 16B-aligned 32B reads.

#define CCH   384          // global row stride (elements)
#define SBB   400          // LDS row stride in BYTES: 384 + 16 pad (25x16B)
#define NPIX  16384
#define BMROWS 64          // pixels per block
#define NTHR  768          // 12 waves; wave owns 32 chans x 64 pixels
#define LNEPS 1e-6f
#define HBUF  (BMROWS * SBB)  // 25600 bytes per buffer
#define WSC   64.0f        // weight pre-scale (pack time)
#define ASC   8.0f         // activation scale (LDS store time)
#define DQ    0.001953125f // 1/(WSC*ASC)
#define SCL1  0x7F7F7F7Fu  // E8M0 scale = 127 in every byte -> 2^0 = 1.0

typedef __attribute__((ext_vector_type(4))) float f4_t;    // 4 x f32
typedef __attribute__((ext_vector_type(8))) int   i32x8;   // 32 B MFMA operand

// workspace offsets (BYTE units). Each 16(chan) x 128(k) fp8 tile = 2048 B.
// K-MAJOR tile order: tile = kb * (N/16) + n16   (kb = K/128 block)
#define OFF_WU 0u
#define OFF_WG 147456u      // 72 tiles * 2048 B
#define OFF_A  294912u
#define OFF_W1 442368u      // 384x1536 -> 288 tiles
#define OFF_W2 1032192u     // 1536x384 -> 288 tiles

__device__ __forceinline__ unsigned char f2e4(float f) {
  __hip_fp8_e4m3 t(f);                       // OCP e4m3fn, HW cvt on gfx950
  return (unsigned char)t.__x;
}

#if __has_builtin(__builtin_amdgcn_cvt_pk_fp8_f32)
__device__ __forceinline__ unsigned pk4e4(float a, float b, float c, float d) {
  int v = __builtin_amdgcn_cvt_pk_fp8_f32(a, b, 0, false);
  v = __builtin_amdgcn_cvt_pk_fp8_f32(c, d, v, true);
  return (unsigned)v;
}
#else
__device__ __forceinline__ unsigned pk4e4(float a, float b, float c, float d) {
  return (unsigned)f2e4(a) | ((unsigned)f2e4(b) << 8)
       | ((unsigned)f2e4(c) << 16) | ((unsigned)f2e4(d) << 24);
}
#endif

__device__ __forceinline__ unsigned short f2bf(float f) {
  return __builtin_bit_cast(unsigned short, __float2bfloat16(f));
}
__device__ __forceinline__ unsigned pack2(float lo, float hi) {
  return (unsigned)f2bf(lo) | ((unsigned)f2bf(hi) << 16);
}
__device__ __forceinline__ float ulo(unsigned u) {
  union { unsigned x; float f; } v; v.x = u << 16; return v.f;
}
__device__ __forceinline__ float uhi(unsigned u) {
  union { unsigned x; float f; } v; v.x = u & 0xffff0000u; return v.f;
}
// sigmoid(z) = 1/(1+2^(-z*log2e))
__device__ __forceinline__ float fsigmoid(float z) {
  return __builtin_amdgcn_rcpf(1.f + exp2f(z * -1.44269504088896f));
}

// Pack all five f32 weights into fp8 MFMA-A fragment order, K=128 tiles:
// P[off + tile*2048 + lane*32 + j] =
//   e4m3(WSC * W[kb*128 + (lane>>4)*32 + j][n16*16 + (lane&15)]), j=0..31
__global__ void pack_all(const float* __restrict__ Wu, const float* __restrict__ Wg,
                         const float* __restrict__ A,  const float* __restrict__ W1,
                         const float* __restrict__ W2, unsigned char* __restrict__ P) {
  const int gid = blockIdx.x * blockDim.x + threadIdx.x;
  const int l = gid & 63;
  int tile = gid >> 6;
  const float* W; int N; unsigned off; int t;
  if      (tile <  72) { W = Wu; N = 384;  off = OFF_WU; t = tile;       }
  else if (tile < 144) { W = Wg; N = 384;  off = OFF_WG; t = tile - 72;  }
  else if (tile < 216) { W = A;  N = 384;  off = OFF_A;  t = tile - 144; }
  else if (tile < 504) { W = W1; N = 1536; off = OFF_W1; t = tile - 216; }
  else if (tile < 792) { W = W2; N = 384;  off = OFF_W2; t = tile - 504; }
  else return;
  const int ntn = N >> 4;
  const int kb  = t / ntn, n16 = t % ntn;
  const int krow = kb * 128 + ((l >> 4) << 5);
  const int col  = n16 * 16 + (l & 15);
  unsigned pk[8];
  #pragma unroll
  for (int d = 0; d < 8; ++d) {
    unsigned v = 0;
    #pragma unroll
    for (int j = 0; j < 4; ++j)
      v |= (unsigned)f2e4(W[(size_t)(krow + d * 4 + j) * N + col] * WSC) << (8 * j);
    pk[d] = v;
  }
  unsigned* dst = reinterpret_cast<unsigned*>(P + off + ((size_t)t << 11) + (l << 5));
  #pragma unroll
  for (int d = 0; d < 8; ++d) dst[d] = pk[d];
}

// acc[4][2] += W^T(2 chan-tiles, packed fp8 K=128) * X^T(LDS fp8, 4 pixel-tiles)
// via MX-scaled MFMA with unit scales. NKB counts K/128 blocks (=3 for K=384).
template <int NKB>
__device__ __forceinline__ void gemm_acc(const unsigned char* sb,
                                         const unsigned char* __restrict__ wt,
                                         int kb0, int ntn, int n16base,
                                         int lane, f4_t acc[4][2]) {
  const int r    = lane & 15;
  const int koff = (lane >> 4) << 5;        // byte offset of 32-k group
  __builtin_amdgcn_s_setprio(1);
  #pragma unroll 1
  for (int kb = 0; kb < NKB; ++kb) {
    const int ac = kb * 128 + koff;
    i32x8 p[4];
    #pragma unroll
    for (int pt = 0; pt < 4; ++pt)
      p[pt] = *reinterpret_cast<const i32x8*>(&sb[(pt * 16 + r) * SBB + ac]);
    const unsigned char* bt =
        wt + (((size_t)((kb0 + kb) * ntn + n16base)) << 11) + (lane << 5);
    #pragma unroll
    for (int ct = 0; ct < 2; ++ct) {
      const i32x8 w = *reinterpret_cast<const i32x8*>(bt + (ct << 11));
      #pragma unroll
      for (int pt = 0; pt < 4; ++pt)
        acc[pt][ct] = __builtin_amdgcn_mfma_scale_f32_16x16x128_f8f6f4(
            w, p[pt], acc[pt][ct], 0 /*fmtA=fp8*/, 0 /*fmtB=fp8*/,
            0, (int)SCL1, 0, (int)SCL1);
    }
  }
  __builtin_amdgcn_s_setprio(0);
}

// write C/D tile (unscaled values) into fp8 LDS [pix][chan] buffer, x ASC:
// each (pt,ct) quad -> one pk4e4 (2 HW cvts) + one ds_write_b32.
__device__ __forceinline__ void write_tile(unsigned char* sb, const f4_t t[4][2],
                                           int ch0, int lane) {
  const int pixb = lane & 15;
  #pragma unroll
  for (int pt = 0; pt < 4; ++pt) {
    const int pix = pt * 16 + pixb;
    #pragma unroll
    for (int ct = 0; ct < 2; ++ct) {
      const unsigned v = pk4e4(t[pt][ct][0] * ASC, t[pt][ct][1] * ASC,
                               t[pt][ct][2] * ASC, t[pt][ct][3] * ASC);
      *reinterpret_cast<unsigned*>(&sb[pix * SBB + ch0 + ct * 16]) = v;
    }
  }
}

__device__ __forceinline__ void zero_acc(f4_t a[4][2]) {
  #pragma unroll
  for (int pt = 0; pt < 4; ++pt)
    #pragma unroll
    for (int ct = 0; ct < 2; ++ct) a[pt][ct] = (f4_t){0.f, 0.f, 0.f, 0.f};
}

__global__ __launch_bounds__(NTHR, 1) void cssm_main(
    const float* __restrict__ x,
    const float* __restrict__ n1s, const float* __restrict__ n1b,
    const float* __restrict__ bu, const float* __restrict__ bg,
    const float* __restrict__ n2s, const float* __restrict__ n2b,
    const float* __restrict__ b1, const float* __restrict__ b2,
    const unsigned char* __restrict__ wp,
    float* __restrict__ out) {
  __shared__ unsigned char sm[3 * HBUF];    // bA | bB | bC (25.6KB each)
  __shared__ float part[BMROWS][12][2];     // per-(pixel,chan-slot) LN2 partials
  __shared__ float srow[BMROWS][2];         // LN2 mu, rs per pixel
  unsigned char* bA = sm;                   // xn -> h ping -> xn2
  unsigned char* bB = sm + HBUF;            // h pong -> m even chunks
  unsigned char* bC = sm + 2 * HBUF;        // m odd chunks

  const int tid = threadIdx.x;
  const int lane = tid & 63;
  const int nw = tid >> 6;                  // chan-slot 0..11: chans nw*32..+31
  const int r0 = blockIdx.x * BMROWS;
  const int pixb = lane & 15;
  const int ch0  = nw * 32 + ((lane >> 4) << 2);   // byte == chan index

  // ---------------- Phase A: LN1(x) -> bA (fp8 x ASC) ----------------------
  if (tid < 512) {
    const int row = tid >> 3, seg = tid & 7;     // 8 thr/row, 48 elems each
    const float* xr = x + (size_t)(r0 + row) * CCH + seg * 48;
    float v[48];
    float s = 0.f, s2 = 0.f;
    #pragma unroll
    for (int i = 0; i < 12; ++i) {
      const f4_t t = reinterpret_cast<const f4_t*>(xr)[i];
      #pragma unroll
      for (int j = 0; j < 4; ++j) { const float f = t[j]; v[i * 4 + j] = f; s += f; s2 += f * f; }
    }
    #pragma unroll
    for (int o = 1; o < 8; o <<= 1) { s += __shfl_xor(s, o, 64); s2 += __shfl_xor(s2, o, 64); }
    const float mu = s * (1.f / CCH);
    const float rs = rsqrtf(fmaxf(s2 * (1.f / CCH) - mu * mu, 0.f) + LNEPS);
    #pragma unroll
    for (int g8 = 0; g8 < 6; ++g8) {
      float w[8];
      #pragma unroll
      for (int j = 0; j < 8; ++j) {
        const int colc = seg * 48 + g8 * 8 + j;
        w[j] = ((v[g8 * 8 + j] - mu) * rs * n1s[colc] + n1b[colc]) * ASC;
      }
      uint2 pk;
      pk.x = pk4e4(w[0], w[1], w[2], w[3]);
      pk.y = pk4e4(w[4], w[5], w[6], w[7]);
      *reinterpret_cast<uint2*>(&bA[row * SBB + seg * 48 + g8 * 8]) = pk;
    }
  }
  __syncthreads();

  // ---------------- Phase A2: g, c -> packed regs; h1 -> bB ----------------
  f4_t acc[4][2];
  unsigned gp[4][2][2], cp[4][2][2];
  zero_acc(acc);
  gemm_acc<3>(bA, wp + OFF_WG, 0, 24, nw * 2, lane, acc);
  #pragma unroll
  for (int ct = 0; ct < 2; ++ct) {
    const f4_t bgq = *reinterpret_cast<const f4_t*>(&bg[ch0 + ct * 16]);
    #pragma unroll
    for (int pt = 0; pt < 4; ++pt) {
      gp[pt][ct][0] = pack2(fsigmoid(acc[pt][ct][0] * DQ + bgq[0]),
                            fsigmoid(acc[pt][ct][1] * DQ + bgq[1]));
      gp[pt][ct][1] = pack2(fsigmoid(acc[pt][ct][2] * DQ + bgq[2]),
                            fsigmoid(acc[pt][ct][3] * DQ + bgq[3]));
    }
  }
  zero_acc(acc);
  gemm_acc<3>(bA, wp + OFF_WU, 0, 24, nw * 2, lane, acc);
  #pragma unroll
  for (int ct = 0; ct < 2; ++ct) {
    const f4_t buq = *reinterpret_cast<const f4_t*>(&bu[ch0 + ct * 16]);
    #pragma unroll
    for (int pt = 0; pt < 4; ++pt) {
      #pragma unroll
      for (int p = 0; p < 2; ++p) {
        const unsigned g = gp[pt][ct][p];
        const float c0 = (1.f - ulo(g)) * (acc[pt][ct][2 * p]     * DQ + buq[2 * p]);
        const float c1 = (1.f - uhi(g)) * (acc[pt][ct][2 * p + 1] * DQ + buq[2 * p + 1]);
        acc[pt][ct][2 * p] = c0; acc[pt][ct][2 * p + 1] = c1;
        cp[pt][ct][p] = pack2(c0, c1);
        // fold DQ into the gate for the recurrence: g' = g*DQ (bf16)
        gp[pt][ct][p] = pack2(ulo(g) * DQ, uhi(g) * DQ);
      }
    }
  }
  write_tile(bB, acc, ch0, lane);           // h1 = c (bA reads done above)
  __syncthreads();

  // ---------------- Phase B: h' = g'*(h@A) + c, ping-pong bB/bA ------------
  {
    unsigned char* cur = bB;
    unsigned char* alt = bA;
    #pragma unroll 1
    for (int stp = 0; stp < 7; ++stp) {     // h2..h8
      zero_acc(acc);
      gemm_acc<3>(cur, wp + OFF_A, 0, 24, nw * 2, lane, acc);
      #pragma unroll
      for (int pt = 0; pt < 4; ++pt)
        #pragma unroll
        for (int ct = 0; ct < 2; ++ct)
          #pragma unroll
          for (int p = 0; p < 2; ++p) {
            const unsigned g = gp[pt][ct][p], c = cp[pt][ct][p];
            acc[pt][ct][2 * p]     = ulo(g) * acc[pt][ct][2 * p]     + ulo(c);
            acc[pt][ct][2 * p + 1] = uhi(g) * acc[pt][ct][2 * p + 1] + uhi(c);
          }
      if (stp < 6) {
        write_tile(alt, acc, ch0, lane);    // write buffer nobody is reading
        unsigned char* t = cur; cur = alt; alt = t;
        __syncthreads();
      }
    }
  }
  // last recurrence reads hit bB (fenced later); bA reads fenced at stp5.

  // ------- Phase C: y = x + h8 -> out (f32 scratch); LN2 -> xn2 in bA ------
  #pragma unroll
  for (int pt = 0; pt < 4; ++pt) {
    const int pix = pt * 16 + pixb;
    float s = 0.f, s2 = 0.f;
    #pragma unroll
    for (int ct = 0; ct < 2; ++ct) {
      const size_t pos = (size_t)(r0 + pix) * CCH + ch0 + ct * 16;
      const f4_t xq = *reinterpret_cast<const f4_t*>(&x[pos]);
      f4_t yq;
      #pragma unroll
      for (int j = 0; j < 4; ++j) {
        const float y = xq[j] + acc[pt][ct][j];
        yq[j] = y; acc[pt][ct][j] = y;
        s += y; s2 += y * y;
      }
      *reinterpret_cast<f4_t*>(&out[pos]) = yq;   // same-thread reread in E
    }
    s += __shfl_xor(s, 16, 64); s2 += __shfl_xor(s2, 16, 64);
    s += __shfl_xor(s, 32, 64); s2 += __shfl_xor(s2, 32, 64);
    if (lane < 16) { part[pix][nw][0] = s; part[pix][nw][1] = s2; }
  }
  __syncthreads();
  if (tid < BMROWS) {
    float s = 0.f, s2 = 0.f;
    #pragma unroll
    for (int w = 0; w < 12; ++w) { s += part[tid][w][0]; s2 += part[tid][w][1]; }
    const float mu = s * (1.f / CCH);
    srow[tid][0] = mu;
    srow[tid][1] = rsqrtf(fmaxf(s2 * (1.f / CCH) - mu * mu, 0.f) + LNEPS);
  }
  __syncthreads();
  {
    f4_t scq[2], bsq[2];
    #pragma unroll
    for (int ct = 0; ct < 2; ++ct) {
      scq[ct] = *reinterpret_cast<const f4_t*>(&n2s[ch0 + ct * 16]);
      bsq[ct] = *reinterpret_cast<const f4_t*>(&n2b[ch0 + ct * 16]);
    }
    #pragma unroll
    for (int pt = 0; pt < 4; ++pt) {
      const int pix = pt * 16 + pixb;
      const float mu = srow[pix][0], rs = srow[pix][1];
      #pragma unroll
      for (int ct = 0; ct < 2; ++ct)
        #pragma unroll
        for (int j = 0; j < 4; ++j)
          acc[pt][ct][j] = (acc[pt][ct][j] - mu) * rs * scq[ct][j] + bsq[ct][j];
    }
    write_tile(bA, acc, ch0, lane);         // xn2 (bA reads fenced at stp5)
  }
  __syncthreads();

  // ------- Phase D: MLP in 4 HID-chunks, m double-buffered bB/bC -----------
  f4_t aco[4][2];
  zero_acc(aco);                            // MFMA-only until E -> AGPR
  #pragma unroll 1
  for (int ch = 0; ch < 4; ++ch) {
    unsigned char* buf = (ch & 1) ? bC : bB;
    zero_acc(acc);
    gemm_acc<3>(bA, wp + OFF_W1, 0, 96, ch * 24 + nw * 2, lane, acc);
    #pragma unroll
    for (int ct = 0; ct < 2; ++ct) {
      const f4_t b1q = *reinterpret_cast<const f4_t*>(&b1[ch * 384 + ch0 + ct * 16]);
      #pragma unroll
      for (int pt = 0; pt < 4; ++pt)
        #pragma unroll
        for (int j = 0; j < 4; ++j) {
          // gelu(z) = z / (1 + 2^(-2.3021178*(z + 0.044715 z^3)))
          const float z = acc[pt][ct][j] * DQ + b1q[j];
          const float m = z * z;
          const float t = z * fmaf(m, 0.044715f, 1.0f);
          const float e = exp2f(t * -2.30211774f);
          acc[pt][ct][j] = z * __builtin_amdgcn_rcpf(1.f + e);
        }
    }
    write_tile(buf, acc, ch0, lane);
    __syncthreads();                        // buf complete; prev buf readers
                                            // passed the previous barrier
    gemm_acc<3>(buf, wp + OFF_W2, ch * 3, 24, nw * 2, lane, aco);
  }

  // ---------------- Phase E: out = y + DQ*mlp + b2 (same-thread reread) ----
  {
    f4_t b2q[2];
    #pragma unroll
    for (int ct = 0; ct < 2; ++ct)
      b2q[ct] = *reinterpret_cast<const f4_t*>(&b2[ch0 + ct * 16]);
    #pragma unroll
    for (int pt = 0; pt < 4; ++pt) {
      const int pix = pt * 16 + pixb;
      #pragma unroll
      for (int ct = 0; ct < 2; ++ct) {
        const size_t pos = (size_t)(r0 + pix) * CCH + ch0 + ct * 16;
        const f4_t yq = *reinterpret_cast<const f4_t*>(&out[pos]);
        f4_t o;
        #pragma unroll
        for (int j = 0; j < 4; ++j)
          o[j] = yq[j] + aco[pt][ct][j] * DQ + b2q[ct][j];
        *reinterpret_cast<f4_t*>(&out[pos]) = o;
      }
    }
  }
}

extern "C" void kernel_launch(void* const* d_in, const int* in_sizes, int n_in,
                              void* d_out, int out_size, void* d_ws, size_t ws_size,
                              hipStream_t stream) {
  const float* x   = (const float*)d_in[0];
  const float* n1s = (const float*)d_in[1];
  const float* n1b = (const float*)d_in[2];
  const float* Wu  = (const float*)d_in[3];
  const float* bu  = (const float*)d_in[4];
  const float* Wg  = (const float*)d_in[5];
  const float* bg  = (const float*)d_in[6];
  const float* A   = (const float*)d_in[7];
  const float* n2s = (const float*)d_in[8];
  const float* n2b = (const float*)d_in[9];
  const float* W1  = (const float*)d_in[10];
  const float* b1  = (const float*)d_in[11];
  const float* W2  = (const float*)d_in[12];
  const float* b2  = (const float*)d_in[13];
  unsigned char* wp = (unsigned char*)d_ws;
  float* out = (float*)d_out;

  // pack all weights to fp8 K=128 fragment order (792 tiles * 64 lanes)
  pack_all<<<(792 * 64) / 256, 256, 0, stream>>>(Wu, Wg, A, W1, W2, wp);

  cssm_main<<<NPIX / BMROWS, NTHR, 0, stream>>>(
      x, n1s, n1b, bu, bg, n2s, n2b, b1, b2, wp, out);
}

// Round 18
// 75.382 us; speedup vs baseline: 3.2522x; 1.0095x over previous
//
#include <hip/hip_runtime.h>
#include <hip/hip_bf16.h>
#include <hip/hip_fp8.h>

// CSSM TinyViT block, fused MFMA implementation for gfx950.
// B=16,H=32,W=32 -> 16384 rows of C=384. T=8, HID=1536.
// Round 18 = round 17 (MX-scaled fp8 MFMA, unit scales) +
//  (1) SBB 432 (108 dwords = 12 mod 32): 32B LDS reads conflict-free,
//  (2) g,c in plain f32 regs (no bf16 unpack in recurrence),
//  (3) LDS convention = "ASC * value" -> write_tile is mul-free; scales
//      folded into gate (g/WSC), LN2 scale/bias, GELU output.

#define CCH   384          // global row stride (elements)
#define SBB   432          // LDS row stride in BYTES (16B-aligned, 12 mod 32 dw)
#define NPIX  16384
#define BMROWS 64          // pixels per block
#define NTHR  768          // 12 waves; wave owns 32 chans x 64 pixels
#define LNEPS 1e-6f
#define HBUF  (BMROWS * SBB)  // 27648 bytes per buffer
#define WSC   64.0f        // weight pre-scale (pack time)
#define ASC   8.0f         // activation scale (LDS store convention)
#define IASC  0.125f       // 1/ASC
#define GSC   0.015625f    // 1/WSC
#define DQ    0.001953125f // 1/(WSC*ASC)
#define SCL1  0x7F7F7F7Fu  // E8M0 scale = 127 in every byte -> 2^0 = 1.0

typedef __attribute__((ext_vector_type(4))) float f4_t;    // 4 x f32
typedef __attribute__((ext_vector_type(8))) int   i32x8;   // 32 B MFMA operand

// workspace offsets (BYTE units). Each 16(chan) x 128(k) fp8 tile = 2048 B.
// K-MAJOR tile order: tile = kb * (N/16) + n16   (kb = K/128 block)
#define OFF_WU 0u
#define OFF_WG 147456u      // 72 tiles * 2048 B
#define OFF_A  294912u
#define OFF_W1 442368u      // 384x1536 -> 288 tiles
#define OFF_W2 1032192u     // 1536x384 -> 288 tiles

__device__ __forceinline__ unsigned char f2e4(float f) {
  __hip_fp8_e4m3 t(f);                       // OCP e4m3fn, HW cvt on gfx950
  return (unsigned char)t.__x;
}

#if __has_builtin(__builtin_amdgcn_cvt_pk_fp8_f32)
__device__ __forceinline__ unsigned pk4e4(float a, float b, float c, float d) {
  int v = __builtin_amdgcn_cvt_pk_fp8_f32(a, b, 0, false);
  v = __builtin_amdgcn_cvt_pk_fp8_f32(c, d, v, true);
  return (unsigned)v;
}
#else
__device__ __forceinline__ unsigned pk4e4(float a, float b, float c, float d) {
  return (unsigned)f2e4(a) | ((unsigned)f2e4(b) << 8)
       | ((unsigned)f2e4(c) << 16) | ((unsigned)f2e4(d) << 24);
}
#endif

// sigmoid(z) = 1/(1+2^(-z*log2e))
__device__ __forceinline__ float fsigmoid(float z) {
  return __builtin_amdgcn_rcpf(1.f + exp2f(z * -1.44269504088896f));
}

// Pack all five f32 weights into fp8 MFMA-A fragment order, K=128 tiles:
// P[off + tile*2048 + lane*32 + j] =
//   e4m3(WSC * W[kb*128 + (lane>>4)*32 + j][n16*16 + (lane&15)]), j=0..31
__global__ void pack_all(const float* __restrict__ Wu, const float* __restrict__ Wg,
                         const float* __restrict__ A,  const float* __restrict__ W1,
                         const float* __restrict__ W2, unsigned char* __restrict__ P) {
  const int gid = blockIdx.x * blockDim.x + threadIdx.x;
  const int l = gid & 63;
  int tile = gid >> 6;
  const float* W; int N; unsigned off; int t;
  if      (tile <  72) { W = Wu; N = 384;  off = OFF_WU; t = tile;       }
  else if (tile < 144) { W = Wg; N = 384;  off = OFF_WG; t = tile - 72;  }
  else if (tile < 216) { W = A;  N = 384;  off = OFF_A;  t = tile - 144; }
  else if (tile < 504) { W = W1; N = 1536; off = OFF_W1; t = tile - 216; }
  else if (tile < 792) { W = W2; N = 384;  off = OFF_W2; t = tile - 504; }
  else return;
  const int ntn = N >> 4;
  const int kb  = t / ntn, n16 = t % ntn;
  const int krow = kb * 128 + ((l >> 4) << 5);
  const int col  = n16 * 16 + (l & 15);
  unsigned pk[8];
  #pragma unroll
  for (int d = 0; d < 8; ++d) {
    unsigned v = 0;
    #pragma unroll
    for (int j = 0; j < 4; ++j)
      v |= (unsigned)f2e4(W[(size_t)(krow + d * 4 + j) * N + col] * WSC) << (8 * j);
    pk[d] = v;
  }
  unsigned* dst = reinterpret_cast<unsigned*>(P + off + ((size_t)t << 11) + (l << 5));
  #pragma unroll
  for (int d = 0; d < 8; ++d) dst[d] = pk[d];
}

// acc[4][2] += W^T(2 chan-tiles, packed fp8 K=128) * X^T(LDS fp8, 4 pixel-tiles)
// via MX-scaled MFMA with unit scales. NKB counts K/128 blocks (=3 for K=384).
template <int NKB>
__device__ __forceinline__ void gemm_acc(const unsigned char* sb,
                                         const unsigned char* __restrict__ wt,
                                         int kb0, int ntn, int n16base,
                                         int lane, f4_t acc[4][2]) {
  const int r    = lane & 15;
  const int koff = (lane >> 4) << 5;        // byte offset of 32-k group
  __builtin_amdgcn_s_setprio(1);
  #pragma unroll 1
  for (int kb = 0; kb < NKB; ++kb) {
    const int ac = kb * 128 + koff;
    i32x8 p[4];
    #pragma unroll
    for (int pt = 0; pt < 4; ++pt)
      p[pt] = *reinterpret_cast<const i32x8*>(&sb[(pt * 16 + r) * SBB + ac]);
    const unsigned char* bt =
        wt + (((size_t)((kb0 + kb) * ntn + n16base)) << 11) + (lane << 5);
    #pragma unroll
    for (int ct = 0; ct < 2; ++ct) {
      const i32x8 w = *reinterpret_cast<const i32x8*>(bt + (ct << 11));
      #pragma unroll
      for (int pt = 0; pt < 4; ++pt)
        acc[pt][ct] = __builtin_amdgcn_mfma_scale_f32_16x16x128_f8f6f4(
            w, p[pt], acc[pt][ct], 0 /*fmtA=fp8*/, 0 /*fmtB=fp8*/,
            0, (int)SCL1, 0, (int)SCL1);
    }
  }
  __builtin_amdgcn_s_setprio(0);
}

// write pre-scaled C/D tile into fp8 LDS [pix][chan]: 2 cvt_pk + 1 write/quad.
__device__ __forceinline__ void write_tile(unsigned char* sb, const f4_t t[4][2],
                                           int ch0, int lane) {
  const int pixb = lane & 15;
  #pragma unroll
  for (int pt = 0; pt < 4; ++pt) {
    const int pix = pt * 16 + pixb;
    #pragma unroll
    for (int ct = 0; ct < 2; ++ct) {
      const unsigned v = pk4e4(t[pt][ct][0], t[pt][ct][1],
                               t[pt][ct][2], t[pt][ct][3]);
      *reinterpret_cast<unsigned*>(&sb[pix * SBB + ch0 + ct * 16]) = v;
    }
  }
}

__device__ __forceinline__ void zero_acc(f4_t a[4][2]) {
  #pragma unroll
  for (int pt = 0; pt < 4; ++pt)
    #pragma unroll
    for (int ct = 0; ct < 2; ++ct) a[pt][ct] = (f4_t){0.f, 0.f, 0.f, 0.f};
}

__global__ __launch_bounds__(NTHR)
__attribute__((amdgpu_waves_per_eu(3)))
void cssm_main(
    const float* __restrict__ x,
    const float* __restrict__ n1s, const float* __restrict__ n1b,
    const float* __restrict__ bu, const float* __restrict__ bg,
    const float* __restrict__ n2s, const float* __restrict__ n2b,
    const float* __restrict__ b1, const float* __restrict__ b2,
    const unsigned char* __restrict__ wp,
    float* __restrict__ out) {
  __shared__ unsigned char sm[3 * HBUF];    // bA | bB | bC (27KB each)
  __shared__ float part[BMROWS][12][2];     // per-(pixel,chan-slot) LN2 partials
  __shared__ float srow[BMROWS][2];         // LN2 mu, rs per pixel
  unsigned char* bA = sm;                   // xn -> h ping -> xn2
  unsigned char* bB = sm + HBUF;            // h pong -> m even chunks
  unsigned char* bC = sm + 2 * HBUF;        // m odd chunks

  const int tid = threadIdx.x;
  const int lane = tid & 63;
  const int nw = tid >> 6;                  // chan-slot 0..11: chans nw*32..+31
  const int r0 = blockIdx.x * BMROWS;
  const int pixb = lane & 15;
  const int ch0  = nw * 32 + ((lane >> 4) << 2);   // byte == chan index

  // ---------------- Phase A: LN1(x) -> bA (fp8, ASC-scaled) ----------------
  if (tid < 512) {
    const int row = tid >> 3, seg = tid & 7;     // 8 thr/row, 48 elems each
    const float* xr = x + (size_t)(r0 + row) * CCH + seg * 48;
    float v[48];
    float s = 0.f, s2 = 0.f;
    #pragma unroll
    for (int i = 0; i < 12; ++i) {
      const f4_t t = reinterpret_cast<const f4_t*>(xr)[i];
      #pragma unroll
      for (int j = 0; j < 4; ++j) { const float f = t[j]; v[i * 4 + j] = f; s += f; s2 += f * f; }
    }
    #pragma unroll
    for (int o = 1; o < 8; o <<= 1) { s += __shfl_xor(s, o, 64); s2 += __shfl_xor(s2, o, 64); }
    const float mu = s * (1.f / CCH);
    const float rs = rsqrtf(fmaxf(s2 * (1.f / CCH) - mu * mu, 0.f) + LNEPS);
    #pragma unroll
    for (int g8 = 0; g8 < 6; ++g8) {
      float w[8];
      #pragma unroll
      for (int j = 0; j < 8; ++j) {
        const int colc = seg * 48 + g8 * 8 + j;
        w[j] = ((v[g8 * 8 + j] - mu) * rs * n1s[colc] + n1b[colc]) * ASC;
      }
      uint2 pk;
      pk.x = pk4e4(w[0], w[1], w[2], w[3]);
      pk.y = pk4e4(w[4], w[5], w[6], w[7]);
      *reinterpret_cast<uint2*>(&bA[row * SBB + seg * 48 + g8 * 8]) = pk;
    }
  }
  __syncthreads();

  // ---------------- Phase A2: gf = g/WSC, cf = ASC*c (f32 regs); h1 -> bB --
  f4_t acc[4][2], gf[4][2], cf[4][2];
  zero_acc(acc);
  gemm_acc<3>(bA, wp + OFF_WG, 0, 24, nw * 2, lane, acc);
  #pragma unroll
  for (int ct = 0; ct < 2; ++ct) {
    const f4_t bgq = *reinterpret_cast<const f4_t*>(&bg[ch0 + ct * 16]);
    #pragma unroll
    for (int pt = 0; pt < 4; ++pt)
      #pragma unroll
      for (int j = 0; j < 4; ++j)
        gf[pt][ct][j] = fsigmoid(acc[pt][ct][j] * DQ + bgq[j]);   // g itself
  }
  zero_acc(acc);
  gemm_acc<3>(bA, wp + OFF_WU, 0, 24, nw * 2, lane, acc);
  #pragma unroll
  for (int ct = 0; ct < 2; ++ct) {
    const f4_t buq = *reinterpret_cast<const f4_t*>(&bu[ch0 + ct * 16]);
    #pragma unroll
    for (int pt = 0; pt < 4; ++pt)
      #pragma unroll
      for (int j = 0; j < 4; ++j) {
        const float g = gf[pt][ct][j];
        cf[pt][ct][j] = (1.f - g) * (acc[pt][ct][j] * DQ + buq[j]) * ASC;
        gf[pt][ct][j] = g * GSC;
      }
  }
  write_tile(bB, cf, ch0, lane);            // H1 = ASC*c  (bA reads done)
  __syncthreads();

  // ---------------- Phase B: H' = gf*raw + cf, ping-pong bB/bA -------------
  {
    unsigned char* cur = bB;
    unsigned char* alt = bA;
    #pragma unroll 1
    for (int stp = 0; stp < 7; ++stp) {     // h2..h8
      zero_acc(acc);
      gemm_acc<3>(cur, wp + OFF_A, 0, 24, nw * 2, lane, acc);
      #pragma unroll
      for (int pt = 0; pt < 4; ++pt)
        #pragma unroll
        for (int ct = 0; ct < 2; ++ct)
          #pragma unroll
          for (int j = 0; j < 4; ++j)
            acc[pt][ct][j] = gf[pt][ct][j] * acc[pt][ct][j] + cf[pt][ct][j];
      if (stp < 6) {
        write_tile(alt, acc, ch0, lane);    // write buffer nobody is reading
        unsigned char* t = cur; cur = alt; alt = t;
        __syncthreads();
      }
    }
  }
  // last recurrence reads hit bB (fenced later); bA reads fenced at stp5.

  // ------- Phase C: y = x + H8/ASC -> out (f32 scratch); LN2 -> xn2 in bA --
  #pragma unroll
  for (int pt = 0; pt < 4; ++pt) {
    const int pix = pt * 16 + pixb;
    float s = 0.f, s2 = 0.f;
    #pragma unroll
    for (int ct = 0; ct < 2; ++ct) {
      const size_t pos = (size_t)(r0 + pix) * CCH + ch0 + ct * 16;
      const f4_t xq = *reinterpret_cast<const f4_t*>(&x[pos]);
      f4_t yq;
      #pragma unroll
      for (int j = 0; j < 4; ++j) {
        const float y = xq[j] + acc[pt][ct][j] * IASC;
        yq[j] = y; acc[pt][ct][j] = y;
        s += y; s2 += y * y;
      }
      *reinterpret_cast<f4_t*>(&out[pos]) = yq;   // same-thread reread in E
    }
    s += __shfl_xor(s, 16, 64); s2 += __shfl_xor(s2, 16, 64);
    s += __shfl_xor(s, 32, 64); s2 += __shfl_xor(s2, 32, 64);
    if (lane < 16) { part[pix][nw][0] = s; part[pix][nw][1] = s2; }
  }
  __syncthreads();
  if (tid < BMROWS) {
    float s = 0.f, s2 = 0.f;
    #pragma unroll
    for (int w = 0; w < 12; ++w) { s += part[tid][w][0]; s2 += part[tid][w][1]; }
    const float mu = s * (1.f / CCH);
    srow[tid][0] = mu;
    srow[tid][1] = rsqrtf(fmaxf(s2 * (1.f / CCH) - mu * mu, 0.f) + LNEPS);
  }
  __syncthreads();
  {
    f4_t scq[2], bsq[2];
    #pragma unroll
    for (int ct = 0; ct < 2; ++ct) {
      const f4_t sc = *reinterpret_cast<const f4_t*>(&n2s[ch0 + ct * 16]);
      const f4_t bs = *reinterpret_cast<const f4_t*>(&n2b[ch0 + ct * 16]);
      #pragma unroll
      for (int j = 0; j < 4; ++j) { scq[ct][j] = sc[j] * ASC; bsq[ct][j] = bs[j] * ASC; }
    }
    #pragma unroll
    for (int pt = 0; pt < 4; ++pt) {
      const int pix = pt * 16 + pixb;
      const float mu = srow[pix][0], rs = srow[pix][1];
      #pragma unroll
      for (int ct = 0; ct < 2; ++ct)
        #pragma unroll
        for (int j = 0; j < 4; ++j)
          acc[pt][ct][j] = (acc[pt][ct][j] - mu) * rs * scq[ct][j] + bsq[ct][j];
    }
    write_tile(bA, acc, ch0, lane);         // ASC*xn2 (bA reads fenced at stp5)
  }
  __syncthreads();

  // ------- Phase D: MLP in 4 HID-chunks, m double-buffered bB/bC -----------
  f4_t aco[4][2];
  zero_acc(aco);                            // MFMA-only until E -> AGPR
  #pragma unroll 1
  for (int ch = 0; ch < 4; ++ch) {
    unsigned char* buf = (ch & 1) ? bC : bB;
    zero_acc(acc);
    gemm_acc<3>(bA, wp + OFF_W1, 0, 96, ch * 24 + nw * 2, lane, acc);
    #pragma unroll
    for (int ct = 0; ct < 2; ++ct) {
      const f4_t b1q = *reinterpret_cast<const f4_t*>(&b1[ch * 384 + ch0 + ct * 16]);
      #pragma unroll
      for (int pt = 0; pt < 4; ++pt)
        #pragma unroll
        for (int j = 0; j < 4; ++j) {
          // gelu(z) = z / (1 + 2^(-2.3021178*(z + 0.044715 z^3))); store ASC*gelu
          const float z = acc[pt][ct][j] * DQ + b1q[j];
          const float m = z * z;
          const float t = z * fmaf(m, 0.044715f, 1.0f);
          const float e = exp2f(t * -2.30211774f);
          acc[pt][ct][j] = (z * ASC) * __builtin_amdgcn_rcpf(1.f + e);
        }
    }
    write_tile(buf, acc, ch0, lane);
    __syncthreads();                        // buf complete; prev buf readers
                                            // passed the previous barrier
    gemm_acc<3>(buf, wp + OFF_W2, ch * 3, 24, nw * 2, lane, aco);
  }

  // ---------------- Phase E: out = y + DQ*mlp + b2 (same-thread reread) ----
  {
    f4_t b2q[2];
    #pragma unroll
    for (int ct = 0; ct < 2; ++ct)
      b2q[ct] = *reinterpret_cast<const f4_t*>(&b2[ch0 + ct * 16]);
    #pragma unroll
    for (int pt = 0; pt < 4; ++pt) {
      const int pix = pt * 16 + pixb;
      #pragma unroll
      for (int ct = 0; ct < 2; ++ct) {
        const size_t pos = (size_t)(r0 + pix) * CCH + ch0 + ct * 16;
        const f4_t yq = *reinterpret_cast<const f4_t*>(&out[pos]);
        f4_t o;
        #pragma unroll
        for (int j = 0; j < 4; ++j)
          o[j] = yq[j] + aco[pt][ct][j] * DQ + b2q[ct][j];
        *reinterpret_cast<f4_t*>(&out[pos]) = o;
      }
    }
  }
}

extern "C" void kernel_launch(void* const* d_in, const int* in_sizes, int n_in,
                              void* d_out, int out_size, void* d_ws, size_t ws_size,
                              hipStream_t stream) {
  const float* x   = (const float*)d_in[0];
  const float* n1s = (const float*)d_in[1];
  const float* n1b = (const float*)d_in[2];
  const float* Wu  = (const float*)d_in[3];
  const float* bu  = (const float*)d_in[4];
  const float* Wg  = (const float*)d_in[5];
  const float* bg  = (const float*)d_in[6];
  const float* A   = (const float*)d_in[7];
  const float* n2s = (const float*)d_in[8];
  const float* n2b = (const float*)d_in[9];
  const float* W1  = (const float*)d_in[10];
  const float* b1  = (const float*)d_in[11];
  const float* W2  = (const float*)d_in[12];
  const float* b2  = (const float*)d_in[13];
  unsigned char* wp = (unsigned char*)d_ws;
  float* out = (float*)d_out;

  // pack all weights to fp8 K=128 fragment order (792 tiles * 64 lanes)
  pack_all<<<(792 * 64) / 256, 256, 0, stream>>>(Wu, Wg, A, W1, W2, wp);

  cssm_main<<<NPIX / BMROWS, NTHR, 0, stream>>>(
      x, n1s, n1b, bu, bg, n2s, n2b, b1, b2, wp, out);
}